// Round 6
// baseline (404.921 us; speedup 1.0000x reference)
//
#include <hip/hip_runtime.h>

// DeformableGCN: 3x mean-smoothing + 2x attention-weighted GCN conv.
// CSR-by-dst, wave-per-dst-node gathers, node-level transforms fused into
// gather epilogues. R1: two-level scan. R2/R3: float4 multi-edge gathers.
// R5: u16 src_idx + fp16 intermediates. R6: xform1 fused into smoothing
// pass 3, xform2 fused into conv1 aggregation (kills 2 kernels + ~50MB of
// round-trips); gather unroll 8/group (32 edges in flight per wave).

typedef __attribute__((ext_vector_type(4))) _Float16 half4;

__global__ void count_deg_kernel(const int* __restrict__ dst, int* __restrict__ deg, int E) {
    int e = blockIdx.x * blockDim.x + threadIdx.x;
    if (e < E) atomicAdd(&deg[dst[e]], 1);
}

__global__ void block_sum_kernel(const int* __restrict__ deg, int* __restrict__ blockSums, int N) {
    __shared__ int sh[256];
    int i = blockIdx.x * 256 + threadIdx.x;
    int v = (i < N) ? deg[i] : 0;
    sh[threadIdx.x] = v;
    __syncthreads();
    for (int off = 128; off > 0; off >>= 1) {
        if (threadIdx.x < off) sh[threadIdx.x] += sh[threadIdx.x + off];
        __syncthreads();
    }
    if (threadIdx.x == 0) blockSums[blockIdx.x] = sh[0];
}

__global__ void scan_sums_kernel(int* __restrict__ blockSums, int* __restrict__ row_ptr_N, int B) {
    __shared__ int sh[1024];
    int t = threadIdx.x;
    int v = (t < B) ? blockSums[t] : 0;
    sh[t] = v;
    __syncthreads();
    for (int off = 1; off < 1024; off <<= 1) {
        int u = (t >= off) ? sh[t - off] : 0;
        __syncthreads();
        sh[t] += u;
        __syncthreads();
    }
    if (t < B) blockSums[t] = sh[t] - v;
    if (t == 1023) row_ptr_N[0] = sh[1023];
}

__global__ void write_rowptr_kernel(const int* __restrict__ deg, const int* __restrict__ blockOffs,
                                    int* __restrict__ row_ptr, int* __restrict__ cursor, int N) {
    __shared__ int sh[256];
    int i = blockIdx.x * 256 + threadIdx.x;
    int v = (i < N) ? deg[i] : 0;
    sh[threadIdx.x] = v;
    __syncthreads();
    for (int off = 1; off < 256; off <<= 1) {
        int u = (threadIdx.x >= off) ? sh[threadIdx.x - off] : 0;
        __syncthreads();
        sh[threadIdx.x] += u;
        __syncthreads();
    }
    if (i < N) {
        int excl = blockOffs[blockIdx.x] + sh[threadIdx.x] - v;
        row_ptr[i] = excl;
        cursor[i] = excl;
    }
}

__global__ void scatter_kernel(const int* __restrict__ src, const int* __restrict__ dst,
                               int* __restrict__ cursor, unsigned short* __restrict__ src_idx,
                               int E) {
    int e = blockIdx.x * blockDim.x + threadIdx.x;
    if (e < E) {
        int slot = atomicAdd(&cursor[dst[e]], 1);
        src_idx[slot] = (unsigned short)src[e];
    }
}

// ---- gather helpers: 4 lane-groups x 16 lanes, unroll 8 per group ----

#define MEAN_GATHER_BODY(LOADV)                                                \
    int beg = row_ptr[n], end = row_ptr[n + 1];                                \
    int j = lane >> 4;                                                         \
    int f = lane & 15;                                                         \
    float4 a0 = make_float4(0.f, 0.f, 0.f, 0.f);                               \
    float4 a1 = make_float4(0.f, 0.f, 0.f, 0.f);                               \
    float4 a2 = make_float4(0.f, 0.f, 0.f, 0.f);                               \
    float4 a3 = make_float4(0.f, 0.f, 0.f, 0.f);                               \
    for (int base = beg + 8 * j; base < end; base += 32) {                     \
        if (base + 8 <= end) {                                                 \
            int s0 = src_idx[base + 0], s1 = src_idx[base + 1];                \
            int s2 = src_idx[base + 2], s3 = src_idx[base + 3];                \
            int s4 = src_idx[base + 4], s5 = src_idx[base + 5];                \
            int s6 = src_idx[base + 6], s7 = src_idx[base + 7];                \
            float4 v0 = LOADV(s0); float4 v1 = LOADV(s1);                      \
            float4 v2 = LOADV(s2); float4 v3 = LOADV(s3);                      \
            float4 v4 = LOADV(s4); float4 v5 = LOADV(s5);                      \
            float4 v6 = LOADV(s6); float4 v7 = LOADV(s7);                      \
            a0.x += v0.x + v4.x; a0.y += v0.y + v4.y;                          \
            a0.z += v0.z + v4.z; a0.w += v0.w + v4.w;                          \
            a1.x += v1.x + v5.x; a1.y += v1.y + v5.y;                          \
            a1.z += v1.z + v5.z; a1.w += v1.w + v5.w;                          \
            a2.x += v2.x + v6.x; a2.y += v2.y + v6.y;                          \
            a2.z += v2.z + v6.z; a2.w += v2.w + v6.w;                          \
            a3.x += v3.x + v7.x; a3.y += v3.y + v7.y;                          \
            a3.z += v3.z + v7.z; a3.w += v3.w + v7.w;                          \
        } else {                                                               \
            for (int e = base; e < end; ++e) {                                 \
                int s = src_idx[e];                                            \
                float4 v = LOADV(s);                                           \
                a0.x += v.x; a0.y += v.y; a0.z += v.z; a0.w += v.w;            \
            }                                                                  \
        }                                                                      \
    }                                                                          \
    a0.x += a1.x + a2.x + a3.x; a0.y += a1.y + a2.y + a3.y;                    \
    a0.z += a1.z + a2.z + a3.z; a0.w += a1.w + a2.w + a3.w;                    \
    a0.x += __shfl_down(a0.x, 32, 64); a0.y += __shfl_down(a0.y, 32, 64);      \
    a0.z += __shfl_down(a0.z, 32, 64); a0.w += __shfl_down(a0.w, 32, 64);      \
    a0.x += __shfl_down(a0.x, 16, 64); a0.y += __shfl_down(a0.y, 16, 64);      \
    a0.z += __shfl_down(a0.z, 16, 64); a0.w += __shfl_down(a0.w, 16, 64);

#define LOAD_F32(s) (*((const float4*)(h + (size_t)(s) * 64) + f))
#define LOAD_F16(s) (make_float4((float)(*((const half4*)(h + (size_t)(s) * 64) + f)).x, \
                                 (float)(*((const half4*)(h + (size_t)(s) * 64) + f)).y, \
                                 (float)(*((const half4*)(h + (size_t)(s) * 64) + f)).z, \
                                 (float)(*((const half4*)(h + (size_t)(s) * 64) + f)).w))

// Smoothing pass 1: fp32 x -> fp16 h1.
__global__ void agg_mean_f32in_kernel(const float* __restrict__ h, const int* __restrict__ row_ptr,
                                      const unsigned short* __restrict__ src_idx,
                                      _Float16* __restrict__ h_out, int N) {
    int wid = (blockIdx.x * blockDim.x + threadIdx.x) >> 6;
    int lane = threadIdx.x & 63;
    if (wid >= N) return;
    int n = wid;
    MEAN_GATHER_BODY(LOAD_F32)
    if (lane < 16) {
        int d = end - beg;
        float inv = d > 0 ? 1.f / (float)d : 0.f;
        half4 o;
        o.x = (_Float16)(a0.x * inv); o.y = (_Float16)(a0.y * inv);
        o.z = (_Float16)(a0.z * inv); o.w = (_Float16)(a0.w * inv);
        *((half4*)(h_out + (size_t)wid * 64) + lane) = o;
    }
}

// Smoothing pass 2: fp16 h1 -> fp16 h2.
__global__ void agg_mean_f16_kernel(const _Float16* __restrict__ h, const int* __restrict__ row_ptr,
                                    const unsigned short* __restrict__ src_idx,
                                    _Float16* __restrict__ h_out, int N) {
    int wid = (blockIdx.x * blockDim.x + threadIdx.x) >> 6;
    int lane = threadIdx.x & 63;
    if (wid >= N) return;
    int n = wid;
    MEAN_GATHER_BODY(LOAD_F16)
    if (lane < 16) {
        int d = end - beg;
        float inv = d > 0 ? 1.f / (float)d : 0.f;
        half4 o;
        o.x = (_Float16)(a0.x * inv); o.y = (_Float16)(a0.y * inv);
        o.z = (_Float16)(a0.z * inv); o.w = (_Float16)(a0.w * inv);
        *((half4*)(h_out + (size_t)wid * 64) + lane) = o;
    }
}

// Smoothing pass 3 fused with conv1 transform: gather h2 -> h3 (registers,
// never stored), xs = (x+h1+h2+h3)/4 -> LDS row -> z1 = xs@W_lin1 (fp16),
// a1/a2 attention dots. No early return (uniform __syncthreads).
__global__ void agg_mean_xform1_kernel(const _Float16* __restrict__ h,  // h2
                                       const float* __restrict__ x,
                                       const _Float16* __restrict__ h1buf,
                                       const int* __restrict__ row_ptr,
                                       const unsigned short* __restrict__ src_idx,
                                       const float* __restrict__ W_lin1,
                                       const float* __restrict__ W_att1,
                                       _Float16* __restrict__ z1, float* __restrict__ a1out,
                                       float* __restrict__ a2out, int N) {
    __shared__ float rows[4][64];
    int w = threadIdx.x >> 6;
    int lane = threadIdx.x & 63;
    int wid = blockIdx.x * 4 + w;
    int n = wid < N ? wid : N - 1;
    MEAN_GATHER_BODY(LOAD_F16)
    if (lane < 16) {
        int d = end - beg;
        float inv = d > 0 ? 1.f / (float)d : 0.f;
        // h3 (fp32, in-register) + x + h1 + h2 of node n
        float4 xv = *((const float4*)(x + (size_t)n * 64) + lane);
        half4 h1v = *((const half4*)(h1buf + (size_t)n * 64) + lane);
        half4 h2v = *((const half4*)(h + (size_t)n * 64) + lane);
        float4 xs;
        xs.x = (xv.x + (float)h1v.x + (float)h2v.x + a0.x * inv) * 0.25f;
        xs.y = (xv.y + (float)h1v.y + (float)h2v.y + a0.y * inv) * 0.25f;
        xs.z = (xv.z + (float)h1v.z + (float)h2v.z + a0.z * inv) * 0.25f;
        xs.w = (xv.w + (float)h1v.w + (float)h2v.w + a0.w * inv) * 0.25f;
        *((float4*)&rows[w][lane * 4]) = xs;
    }
    __syncthreads();
    float xv = rows[w][lane];
    float p1 = xv * W_att1[lane];
    float p2 = xv * W_att1[64 + lane];
    for (int off = 32; off > 0; off >>= 1) {
        p1 += __shfl_down(p1, off, 64);
        p2 += __shfl_down(p2, off, 64);
    }
    float acc = 0.f;
    #pragma unroll
    for (int k = 0; k < 64; ++k) acc += rows[w][k] * W_lin1[k * 64 + lane];
    if (wid < N) {
        z1[(size_t)wid * 64 + lane] = (_Float16)acc;
        if (lane == 0) { a1out[wid] = p1; a2out[wid] = p2; }
    }
}

// Conv1 aggregation fused with conv2 transform: gather z1 with per-edge
// leaky scores -> relu -> h1 row (LDS, never stored globally) -> z2 = h1@W_lin2,
// a1b/a2b dots. No early return (uniform __syncthreads).
__global__ void agg_conv64_xform2_kernel(const _Float16* __restrict__ z,
                                         const float* __restrict__ a1v,
                                         const float* __restrict__ a2v,
                                         const float* __restrict__ b_att,
                                         const int* __restrict__ row_ptr,
                                         const unsigned short* __restrict__ src_idx,
                                         const float* __restrict__ W_lin2,
                                         const float* __restrict__ W_att2,
                                         float* __restrict__ z2, float* __restrict__ a1out,
                                         float* __restrict__ a2out, int N) {
    __shared__ float rows[4][64];
    int w = threadIdx.x >> 6;
    int lane = threadIdx.x & 63;
    int wid = blockIdx.x * 4 + w;
    int n = wid < N ? wid : N - 1;
    float ad = a2v[n] + b_att[0];
    int beg = row_ptr[n], end = row_ptr[n + 1];
    int j = lane >> 4;
    int f = lane & 15;
    float4 a0 = make_float4(0.f, 0.f, 0.f, 0.f);
    float4 a1 = make_float4(0.f, 0.f, 0.f, 0.f);
    float4 a2 = make_float4(0.f, 0.f, 0.f, 0.f);
    float4 a3 = make_float4(0.f, 0.f, 0.f, 0.f);
    for (int base = beg + 8 * j; base < end; base += 32) {
        if (base + 8 <= end) {
            int s0 = src_idx[base + 0], s1 = src_idx[base + 1];
            int s2 = src_idx[base + 2], s3 = src_idx[base + 3];
            int s4 = src_idx[base + 4], s5 = src_idx[base + 5];
            int s6 = src_idx[base + 6], s7 = src_idx[base + 7];
            float sc0 = a1v[s0] + ad; sc0 = sc0 > 0.f ? sc0 : 0.01f * sc0;
            float sc1 = a1v[s1] + ad; sc1 = sc1 > 0.f ? sc1 : 0.01f * sc1;
            float sc2 = a1v[s2] + ad; sc2 = sc2 > 0.f ? sc2 : 0.01f * sc2;
            float sc3 = a1v[s3] + ad; sc3 = sc3 > 0.f ? sc3 : 0.01f * sc3;
            float sc4 = a1v[s4] + ad; sc4 = sc4 > 0.f ? sc4 : 0.01f * sc4;
            float sc5 = a1v[s5] + ad; sc5 = sc5 > 0.f ? sc5 : 0.01f * sc5;
            float sc6 = a1v[s6] + ad; sc6 = sc6 > 0.f ? sc6 : 0.01f * sc6;
            float sc7 = a1v[s7] + ad; sc7 = sc7 > 0.f ? sc7 : 0.01f * sc7;
            half4 v0 = *((const half4*)(z + (size_t)s0 * 64) + f);
            half4 v1 = *((const half4*)(z + (size_t)s1 * 64) + f);
            half4 v2 = *((const half4*)(z + (size_t)s2 * 64) + f);
            half4 v3 = *((const half4*)(z + (size_t)s3 * 64) + f);
            half4 v4 = *((const half4*)(z + (size_t)s4 * 64) + f);
            half4 v5 = *((const half4*)(z + (size_t)s5 * 64) + f);
            half4 v6 = *((const half4*)(z + (size_t)s6 * 64) + f);
            half4 v7 = *((const half4*)(z + (size_t)s7 * 64) + f);
            a0.x += sc0 * (float)v0.x + sc4 * (float)v4.x;
            a0.y += sc0 * (float)v0.y + sc4 * (float)v4.y;
            a0.z += sc0 * (float)v0.z + sc4 * (float)v4.z;
            a0.w += sc0 * (float)v0.w + sc4 * (float)v4.w;
            a1.x += sc1 * (float)v1.x + sc5 * (float)v5.x;
            a1.y += sc1 * (float)v1.y + sc5 * (float)v5.y;
            a1.z += sc1 * (float)v1.z + sc5 * (float)v5.z;
            a1.w += sc1 * (float)v1.w + sc5 * (float)v5.w;
            a2.x += sc2 * (float)v2.x + sc6 * (float)v6.x;
            a2.y += sc2 * (float)v2.y + sc6 * (float)v6.y;
            a2.z += sc2 * (float)v2.z + sc6 * (float)v6.z;
            a2.w += sc2 * (float)v2.w + sc6 * (float)v6.w;
            a3.x += sc3 * (float)v3.x + sc7 * (float)v7.x;
            a3.y += sc3 * (float)v3.y + sc7 * (float)v7.y;
            a3.z += sc3 * (float)v3.z + sc7 * (float)v7.z;
            a3.w += sc3 * (float)v3.w + sc7 * (float)v7.w;
        } else {
            for (int e = base; e < end; ++e) {
                int s = src_idx[e];
                float sc = a1v[s] + ad; sc = sc > 0.f ? sc : 0.01f * sc;
                half4 v = *((const half4*)(z + (size_t)s * 64) + f);
                a0.x += sc * (float)v.x; a0.y += sc * (float)v.y;
                a0.z += sc * (float)v.z; a0.w += sc * (float)v.w;
            }
        }
    }
    a0.x += a1.x + a2.x + a3.x; a0.y += a1.y + a2.y + a3.y;
    a0.z += a1.z + a2.z + a3.z; a0.w += a1.w + a2.w + a3.w;
    a0.x += __shfl_down(a0.x, 32, 64); a0.y += __shfl_down(a0.y, 32, 64);
    a0.z += __shfl_down(a0.z, 32, 64); a0.w += __shfl_down(a0.w, 32, 64);
    a0.x += __shfl_down(a0.x, 16, 64); a0.y += __shfl_down(a0.y, 16, 64);
    a0.z += __shfl_down(a0.z, 16, 64); a0.w += __shfl_down(a0.w, 16, 64);
    if (lane < 16) {
        float4 o;
        o.x = fmaxf(a0.x, 0.f); o.y = fmaxf(a0.y, 0.f);
        o.z = fmaxf(a0.z, 0.f); o.w = fmaxf(a0.w, 0.f);
        *((float4*)&rows[w][lane * 4]) = o;
    }
    __syncthreads();
    float hv = rows[w][lane];
    float p1 = hv * W_att2[lane];
    float p2 = hv * W_att2[64 + lane];
    for (int off = 32; off > 0; off >>= 1) {
        p1 += __shfl_down(p1, off, 64);
        p2 += __shfl_down(p2, off, 64);
    }
    float acc = 0.f;
    if (lane < 32) {
        #pragma unroll
        for (int k = 0; k < 64; ++k) acc += rows[w][k] * W_lin2[k * 32 + lane];
    }
    if (wid < N) {
        if (lane < 32) z2[(size_t)wid * 32 + lane] = acc;
        if (lane == 0) { a1out[wid] = p1; a2out[wid] = p2; }
    }
}

// Conv2 aggregation (D=32): 8 lane-groups x 8 lanes, 4 edges/group in flight.
__global__ void agg_conv32_kernel(const float* __restrict__ z, const float* __restrict__ a1v,
                                  const float* __restrict__ a2v, const float* __restrict__ b_att,
                                  const int* __restrict__ row_ptr,
                                  const unsigned short* __restrict__ src_idx,
                                  float* __restrict__ outp, int N) {
    int wid = (blockIdx.x * blockDim.x + threadIdx.x) >> 6;
    int lane = threadIdx.x & 63;
    if (wid >= N) return;
    float ad = a2v[wid] + b_att[0];
    int beg = row_ptr[wid], end = row_ptr[wid + 1];
    int j = lane >> 3;
    int f = lane & 7;
    float4 a0 = make_float4(0.f, 0.f, 0.f, 0.f);
    float4 a1 = make_float4(0.f, 0.f, 0.f, 0.f);
    for (int base = beg + 4 * j; base < end; base += 32) {
        if (base + 4 <= end) {
            int s0 = src_idx[base + 0], s1 = src_idx[base + 1];
            int s2 = src_idx[base + 2], s3 = src_idx[base + 3];
            float sc0 = a1v[s0] + ad; sc0 = sc0 > 0.f ? sc0 : 0.01f * sc0;
            float sc1 = a1v[s1] + ad; sc1 = sc1 > 0.f ? sc1 : 0.01f * sc1;
            float sc2 = a1v[s2] + ad; sc2 = sc2 > 0.f ? sc2 : 0.01f * sc2;
            float sc3 = a1v[s3] + ad; sc3 = sc3 > 0.f ? sc3 : 0.01f * sc3;
            float4 v0 = *((const float4*)(z + (size_t)s0 * 32) + f);
            float4 v1 = *((const float4*)(z + (size_t)s1 * 32) + f);
            float4 v2 = *((const float4*)(z + (size_t)s2 * 32) + f);
            float4 v3 = *((const float4*)(z + (size_t)s3 * 32) + f);
            a0.x += sc0 * v0.x + sc2 * v2.x; a0.y += sc0 * v0.y + sc2 * v2.y;
            a0.z += sc0 * v0.z + sc2 * v2.z; a0.w += sc0 * v0.w + sc2 * v2.w;
            a1.x += sc1 * v1.x + sc3 * v3.x; a1.y += sc1 * v1.y + sc3 * v3.y;
            a1.z += sc1 * v1.z + sc3 * v3.z; a1.w += sc1 * v1.w + sc3 * v3.w;
        } else {
            for (int e = base; e < end; ++e) {
                int s = src_idx[e];
                float sc = a1v[s] + ad; sc = sc > 0.f ? sc : 0.01f * sc;
                float4 v = *((const float4*)(z + (size_t)s * 32) + f);
                a0.x += sc * v.x; a0.y += sc * v.y; a0.z += sc * v.z; a0.w += sc * v.w;
            }
        }
    }
    a0.x += a1.x; a0.y += a1.y; a0.z += a1.z; a0.w += a1.w;
    a0.x += __shfl_down(a0.x, 32, 64); a0.y += __shfl_down(a0.y, 32, 64);
    a0.z += __shfl_down(a0.z, 32, 64); a0.w += __shfl_down(a0.w, 32, 64);
    a0.x += __shfl_down(a0.x, 16, 64); a0.y += __shfl_down(a0.y, 16, 64);
    a0.z += __shfl_down(a0.z, 16, 64); a0.w += __shfl_down(a0.w, 16, 64);
    a0.x += __shfl_down(a0.x, 8, 64);  a0.y += __shfl_down(a0.y, 8, 64);
    a0.z += __shfl_down(a0.z, 8, 64);  a0.w += __shfl_down(a0.w, 8, 64);
    if (lane < 8) {
        *((float4*)(outp + (size_t)wid * 32) + lane) = a0;
    }
}

extern "C" void kernel_launch(void* const* d_in, const int* in_sizes, int n_in,
                              void* d_out, int out_size, void* d_ws, size_t ws_size,
                              hipStream_t stream) {
    const float* x      = (const float*)d_in[0];
    const int*   ei     = (const int*)d_in[1];
    const float* W_att1 = (const float*)d_in[2];
    const float* b_att1 = (const float*)d_in[3];
    const float* W_lin1 = (const float*)d_in[4];
    const float* W_att2 = (const float*)d_in[5];
    const float* b_att2 = (const float*)d_in[6];
    const float* W_lin2 = (const float*)d_in[7];
    float* out = (float*)d_out;

    int N = in_sizes[0] / 64;   // 50000 (< 65536, required for u16 src_idx)
    int E = in_sizes[1] / 2;
    const int* src = ei;
    const int* dst = ei + E;

    char* ws = (char*)d_ws;
    size_t off = 0;
    auto alloc = [&](size_t bytes) -> void* {
        void* p = ws + off;
        off += (bytes + 255) & ~(size_t)255;
        return p;
    };
    int*            deg       = (int*)alloc((size_t)N * 4);
    int*            row_ptr   = (int*)alloc((size_t)(N + 1) * 4);
    int*            cursor    = (int*)alloc((size_t)N * 4);
    unsigned short* src_idx   = (unsigned short*)alloc((size_t)E * 2);
    int*            blockSums = (int*)alloc((size_t)1024 * 4);
    _Float16* hA = (_Float16*)alloc((size_t)N * 64 * 2);   // h1 (smoothing)
    _Float16* hB = (_Float16*)alloc((size_t)N * 64 * 2);   // h2
    _Float16* z1 = (_Float16*)alloc((size_t)N * 64 * 2);   // conv1 lin output
    float* z2  = (float*)alloc((size_t)N * 32 * 4);        // conv2 lin output
    float* a1  = (float*)alloc((size_t)N * 4);
    float* a2  = (float*)alloc((size_t)N * 4);
    float* a1b = (float*)alloc((size_t)N * 4);
    float* a2b = (float*)alloc((size_t)N * 4);

    const int tb = 256;
    hipMemsetAsync(deg, 0, (size_t)N * 4, stream);
    count_deg_kernel<<<(E + tb - 1) / tb, tb, 0, stream>>>(dst, deg, E);

    int B = (N + 255) / 256;
    block_sum_kernel<<<B, 256, 0, stream>>>(deg, blockSums, N);
    scan_sums_kernel<<<1, 1024, 0, stream>>>(blockSums, row_ptr + N, B);
    write_rowptr_kernel<<<B, 256, 0, stream>>>(deg, blockSums, row_ptr, cursor, N);

    scatter_kernel<<<(E + tb - 1) / tb, tb, 0, stream>>>(src, dst, cursor, src_idx, E);

    int nodeBlocks = (N + 3) / 4;   // one wave (64 lanes) per node, 4 waves/block
    agg_mean_f32in_kernel<<<nodeBlocks, tb, 0, stream>>>(x,  row_ptr, src_idx, hA, N);
    agg_mean_f16_kernel<<<nodeBlocks, tb, 0, stream>>>(hA, row_ptr, src_idx, hB, N);
    agg_mean_xform1_kernel<<<nodeBlocks, tb, 0, stream>>>(hB, x, hA, row_ptr, src_idx,
                                                          W_lin1, W_att1, z1, a1, a2, N);
    agg_conv64_xform2_kernel<<<nodeBlocks, tb, 0, stream>>>(z1, a1, a2, b_att1, row_ptr, src_idx,
                                                            W_lin2, W_att2, z2, a1b, a2b, N);
    agg_conv32_kernel<<<nodeBlocks, tb, 0, stream>>>(z2, a1b, a2b, b_att2, row_ptr, src_idx,
                                                     out, N);
}

// Round 7
// 316.222 us; speedup vs baseline: 1.2805x; 1.2805x over previous
//
#include <hip/hip_runtime.h>

// DeformableGCN: 3x mean-smoothing + 2x attention-weighted GCN conv.
// CSR-by-dst, wave-per-dst-node gathers, separate node-level transforms.
// R1: two-level scan. R2/R3: multi-edge gathers. R5: u16 src_idx + fp16
// intermediates. R6 fusion REVERTED (syncthreads couples waves to block-max
// degree; scalar tails serialize). R7: 8-lane-group half8/float4 gathers
// (1 load inst = 8 edges), fully branchless predication (clamp+cndmask) so
// all 32 edge-loads per wave issue before any wait.

typedef __attribute__((ext_vector_type(8))) _Float16 half8;
typedef __attribute__((ext_vector_type(4))) _Float16 half4;

__global__ void count_deg_kernel(const int* __restrict__ dst, int* __restrict__ deg, int E) {
    int e = blockIdx.x * blockDim.x + threadIdx.x;
    if (e < E) atomicAdd(&deg[dst[e]], 1);
}

__global__ void block_sum_kernel(const int* __restrict__ deg, int* __restrict__ blockSums, int N) {
    __shared__ int sh[256];
    int i = blockIdx.x * 256 + threadIdx.x;
    int v = (i < N) ? deg[i] : 0;
    sh[threadIdx.x] = v;
    __syncthreads();
    for (int off = 128; off > 0; off >>= 1) {
        if (threadIdx.x < off) sh[threadIdx.x] += sh[threadIdx.x + off];
        __syncthreads();
    }
    if (threadIdx.x == 0) blockSums[blockIdx.x] = sh[0];
}

__global__ void scan_sums_kernel(int* __restrict__ blockSums, int* __restrict__ row_ptr_N, int B) {
    __shared__ int sh[1024];
    int t = threadIdx.x;
    int v = (t < B) ? blockSums[t] : 0;
    sh[t] = v;
    __syncthreads();
    for (int off = 1; off < 1024; off <<= 1) {
        int u = (t >= off) ? sh[t - off] : 0;
        __syncthreads();
        sh[t] += u;
        __syncthreads();
    }
    if (t < B) blockSums[t] = sh[t] - v;
    if (t == 1023) row_ptr_N[0] = sh[1023];
}

__global__ void write_rowptr_kernel(const int* __restrict__ deg, const int* __restrict__ blockOffs,
                                    int* __restrict__ row_ptr, int* __restrict__ cursor, int N) {
    __shared__ int sh[256];
    int i = blockIdx.x * 256 + threadIdx.x;
    int v = (i < N) ? deg[i] : 0;
    sh[threadIdx.x] = v;
    __syncthreads();
    for (int off = 1; off < 256; off <<= 1) {
        int u = (threadIdx.x >= off) ? sh[threadIdx.x - off] : 0;
        __syncthreads();
        sh[threadIdx.x] += u;
        __syncthreads();
    }
    if (i < N) {
        int excl = blockOffs[blockIdx.x] + sh[threadIdx.x] - v;
        row_ptr[i] = excl;
        cursor[i] = excl;
    }
}

__global__ void scatter_kernel(const int* __restrict__ src, const int* __restrict__ dst,
                               int* __restrict__ cursor, unsigned short* __restrict__ src_idx,
                               int E) {
    int e = blockIdx.x * blockDim.x + threadIdx.x;
    if (e < E) {
        int slot = atomicAdd(&cursor[dst[e]], 1);
        src_idx[slot] = (unsigned short)src[e];
    }
}

// x (fp32) -> x16 (fp16), one half8 per thread.
__global__ void cvt_x_kernel(const float* __restrict__ x, _Float16* __restrict__ x16, int total8) {
    int i = blockIdx.x * blockDim.x + threadIdx.x;
    if (i >= total8) return;
    float4 v0 = ((const float4*)x)[2 * i];
    float4 v1 = ((const float4*)x)[2 * i + 1];
    half8 o;
    o[0] = (_Float16)v0.x; o[1] = (_Float16)v0.y; o[2] = (_Float16)v0.z; o[3] = (_Float16)v0.w;
    o[4] = (_Float16)v1.x; o[5] = (_Float16)v1.y; o[6] = (_Float16)v1.z; o[7] = (_Float16)v1.w;
    ((half8*)x16)[i] = o;
}

// Mean aggregation over fp16 rows (128B = 8 lanes x half8). One wave per
// node, 8 groups x 8 lanes, 4 predicated slots/group = 32 edges in flight.
__global__ void agg_mean8_kernel(const _Float16* __restrict__ h, const int* __restrict__ row_ptr,
                                 const unsigned short* __restrict__ src_idx,
                                 _Float16* __restrict__ h_out, int N) {
    int wid = (blockIdx.x * blockDim.x + threadIdx.x) >> 6;
    int lane = threadIdx.x & 63;
    if (wid >= N) return;
    int beg = row_ptr[wid], end = row_ptr[wid + 1];
    int j = lane >> 3, f = lane & 7;
    const uint4* rowp = (const uint4*)h;   // row stride 8 uint4s
    float acc[8];
    #pragma unroll
    for (int q = 0; q < 8; ++q) acc[q] = 0.f;
    for (int base = beg + 4 * j; base < end; base += 32) {
        #pragma unroll
        for (int k = 0; k < 4; ++k) {
            int e = base + k;
            int ec = e < end ? e : base;             // clamp: base < end here
            int s = src_idx[ec];
            uint4 raw = rowp[(size_t)s * 8 + f];
            if (e >= end) { raw.x = 0u; raw.y = 0u; raw.z = 0u; raw.w = 0u; }
            half8 v = *(half8*)&raw;
            #pragma unroll
            for (int q = 0; q < 8; ++q) acc[q] += (float)v[q];
        }
    }
    #pragma unroll
    for (int q = 0; q < 8; ++q) {
        acc[q] += __shfl_down(acc[q], 32, 64);
        acc[q] += __shfl_down(acc[q], 16, 64);
        acc[q] += __shfl_down(acc[q], 8, 64);
    }
    if (lane < 8) {
        int d = end - beg;
        float inv = d > 0 ? 1.f / (float)d : 0.f;
        half8 o;
        #pragma unroll
        for (int q = 0; q < 8; ++q) o[q] = (_Float16)(acc[q] * inv);
        *((half8*)h_out + (size_t)wid * 8 + lane) = o;
    }
}

// Conv1 transform: xs = (x+h1+h2+h3)/4. z1 = xs@W_lin1 (fp16), a1/a2 dots.
__global__ void xform1_kernel(const float* __restrict__ x, const _Float16* __restrict__ hA,
                              const _Float16* __restrict__ hB, const _Float16* __restrict__ hC,
                              const float* __restrict__ W_lin1, const float* __restrict__ W_att1,
                              _Float16* __restrict__ z1, float* __restrict__ a1,
                              float* __restrict__ a2, int N) {
    __shared__ float row[4][64];
    int wib = threadIdx.x >> 6;
    int lane = threadIdx.x & 63;
    int n = blockIdx.x * 4 + wib;
    int nc = n < N ? n : N - 1;
    size_t idx = (size_t)nc * 64 + lane;
    float xv = (x[idx] + (float)hA[idx] + (float)hB[idx] + (float)hC[idx]) * 0.25f;
    row[wib][lane] = xv;
    __syncthreads();
    float p1 = xv * W_att1[lane];
    float p2 = xv * W_att1[64 + lane];
    for (int off = 32; off > 0; off >>= 1) {
        p1 += __shfl_down(p1, off, 64);
        p2 += __shfl_down(p2, off, 64);
    }
    float acc = 0.f;
    #pragma unroll
    for (int k = 0; k < 64; ++k) acc += row[wib][k] * W_lin1[k * 64 + lane];
    if (n < N) {
        z1[(size_t)n * 64 + lane] = (_Float16)acc;
        if (lane == 0) { a1[n] = p1; a2[n] = p2; }
    }
}

__global__ void xform2_kernel(const float* __restrict__ h1, const float* __restrict__ W_lin2,
                              const float* __restrict__ W_att2,
                              float* __restrict__ z2, float* __restrict__ a1, float* __restrict__ a2,
                              int N) {
    __shared__ float row[4][64];
    int wib = threadIdx.x >> 6;
    int lane = threadIdx.x & 63;
    int n = blockIdx.x * 4 + wib;
    int nc = n < N ? n : N - 1;
    float hv = h1[(size_t)nc * 64 + lane];
    row[wib][lane] = hv;
    __syncthreads();
    float p1 = hv * W_att2[lane];
    float p2 = hv * W_att2[64 + lane];
    for (int off = 32; off > 0; off >>= 1) {
        p1 += __shfl_down(p1, off, 64);
        p2 += __shfl_down(p2, off, 64);
    }
    float acc = 0.f;
    if (lane < 32) {
        #pragma unroll
        for (int k = 0; k < 64; ++k) acc += row[wib][k] * W_lin2[k * 32 + lane];
    }
    if (n < N) {
        if (lane < 32) z2[(size_t)n * 32 + lane] = acc;
        if (lane == 0) { a1[n] = p1; a2[n] = p2; }
    }
}

// Conv1 aggregation: fp16 z1 rows, 8-lane groups, per-edge leaky score,
// relu -> fp32 out. Branchless predication, 32 edges in flight per wave.
__global__ void agg_conv64_kernel(const _Float16* __restrict__ z, const float* __restrict__ a1v,
                                  const float* __restrict__ a2v, const float* __restrict__ b_att,
                                  const int* __restrict__ row_ptr,
                                  const unsigned short* __restrict__ src_idx,
                                  float* __restrict__ outp, int N) {
    int wid = (blockIdx.x * blockDim.x + threadIdx.x) >> 6;
    int lane = threadIdx.x & 63;
    if (wid >= N) return;
    float ad = a2v[wid] + b_att[0];
    int beg = row_ptr[wid], end = row_ptr[wid + 1];
    int j = lane >> 3, f = lane & 7;
    const uint4* rowp = (const uint4*)z;
    float acc[8];
    #pragma unroll
    for (int q = 0; q < 8; ++q) acc[q] = 0.f;
    for (int base = beg + 4 * j; base < end; base += 32) {
        #pragma unroll
        for (int k = 0; k < 4; ++k) {
            int e = base + k;
            int ec = e < end ? e : base;
            int s = src_idx[ec];
            float sc = a1v[s] + ad;
            sc = sc > 0.f ? sc : 0.01f * sc;
            uint4 raw = rowp[(size_t)s * 8 + f];
            if (e >= end) { raw.x = 0u; raw.y = 0u; raw.z = 0u; raw.w = 0u; }
            half8 v = *(half8*)&raw;
            #pragma unroll
            for (int q = 0; q < 8; ++q) acc[q] += sc * (float)v[q];
        }
    }
    #pragma unroll
    for (int q = 0; q < 8; ++q) {
        acc[q] += __shfl_down(acc[q], 32, 64);
        acc[q] += __shfl_down(acc[q], 16, 64);
        acc[q] += __shfl_down(acc[q], 8, 64);
    }
    if (lane < 8) {
        float4 o0, o1;
        o0.x = fmaxf(acc[0], 0.f); o0.y = fmaxf(acc[1], 0.f);
        o0.z = fmaxf(acc[2], 0.f); o0.w = fmaxf(acc[3], 0.f);
        o1.x = fmaxf(acc[4], 0.f); o1.y = fmaxf(acc[5], 0.f);
        o1.z = fmaxf(acc[6], 0.f); o1.w = fmaxf(acc[7], 0.f);
        float4* op = (float4*)(outp + (size_t)wid * 64 + lane * 8);
        op[0] = o0; op[1] = o1;
    }
}

// Conv2 aggregation: fp32 z2 rows (128B = 8 lanes x float4), 8-lane groups,
// branchless predication, 32 edges in flight.
__global__ void agg_conv32_kernel(const float* __restrict__ z, const float* __restrict__ a1v,
                                  const float* __restrict__ a2v, const float* __restrict__ b_att,
                                  const int* __restrict__ row_ptr,
                                  const unsigned short* __restrict__ src_idx,
                                  float* __restrict__ outp, int N) {
    int wid = (blockIdx.x * blockDim.x + threadIdx.x) >> 6;
    int lane = threadIdx.x & 63;
    if (wid >= N) return;
    float ad = a2v[wid] + b_att[0];
    int beg = row_ptr[wid], end = row_ptr[wid + 1];
    int j = lane >> 3, f = lane & 7;
    const float4* rowp = (const float4*)z;   // row stride 8 float4s
    float ax = 0.f, ay = 0.f, az = 0.f, aw = 0.f;
    for (int base = beg + 4 * j; base < end; base += 32) {
        #pragma unroll
        for (int k = 0; k < 4; ++k) {
            int e = base + k;
            int ec = e < end ? e : base;
            int s = src_idx[ec];
            float sc = a1v[s] + ad;
            sc = sc > 0.f ? sc : 0.01f * sc;
            if (e >= end) sc = 0.f;
            float4 v = rowp[(size_t)s * 8 + f];
            ax += sc * v.x; ay += sc * v.y; az += sc * v.z; aw += sc * v.w;
        }
    }
    ax += __shfl_down(ax, 32, 64); ay += __shfl_down(ay, 32, 64);
    az += __shfl_down(az, 32, 64); aw += __shfl_down(aw, 32, 64);
    ax += __shfl_down(ax, 16, 64); ay += __shfl_down(ay, 16, 64);
    az += __shfl_down(az, 16, 64); aw += __shfl_down(aw, 16, 64);
    ax += __shfl_down(ax, 8, 64);  ay += __shfl_down(ay, 8, 64);
    az += __shfl_down(az, 8, 64);  aw += __shfl_down(aw, 8, 64);
    if (lane < 8) {
        float4 o; o.x = ax; o.y = ay; o.z = az; o.w = aw;
        *((float4*)(outp + (size_t)wid * 32) + lane) = o;
    }
}

extern "C" void kernel_launch(void* const* d_in, const int* in_sizes, int n_in,
                              void* d_out, int out_size, void* d_ws, size_t ws_size,
                              hipStream_t stream) {
    const float* x      = (const float*)d_in[0];
    const int*   ei     = (const int*)d_in[1];
    const float* W_att1 = (const float*)d_in[2];
    const float* b_att1 = (const float*)d_in[3];
    const float* W_lin1 = (const float*)d_in[4];
    const float* W_att2 = (const float*)d_in[5];
    const float* b_att2 = (const float*)d_in[6];
    const float* W_lin2 = (const float*)d_in[7];
    float* out = (float*)d_out;

    int N = in_sizes[0] / 64;   // 50000 (< 65536, required for u16 src_idx)
    int E = in_sizes[1] / 2;
    const int* src = ei;
    const int* dst = ei + E;

    char* ws = (char*)d_ws;
    size_t off = 0;
    auto alloc = [&](size_t bytes) -> void* {
        void* p = ws + off;
        off += (bytes + 255) & ~(size_t)255;
        return p;
    };
    int*            deg       = (int*)alloc((size_t)N * 4);
    int*            row_ptr   = (int*)alloc((size_t)(N + 1) * 4);
    int*            cursor    = (int*)alloc((size_t)N * 4);
    unsigned short* src_idx   = (unsigned short*)alloc((size_t)E * 2);
    int*            blockSums = (int*)alloc((size_t)1024 * 4);
    _Float16* x16 = (_Float16*)alloc((size_t)N * 64 * 2);
    _Float16* hA  = (_Float16*)alloc((size_t)N * 64 * 2);
    _Float16* hB  = (_Float16*)alloc((size_t)N * 64 * 2);
    _Float16* hC  = (_Float16*)alloc((size_t)N * 64 * 2);
    _Float16* z1  = (_Float16*)alloc((size_t)N * 64 * 2);
    float* h1c = (float*)alloc((size_t)N * 64 * 4);
    float* z2  = (float*)alloc((size_t)N * 32 * 4);
    float* a1  = (float*)alloc((size_t)N * 4);
    float* a2  = (float*)alloc((size_t)N * 4);
    float* a1b = (float*)alloc((size_t)N * 4);
    float* a2b = (float*)alloc((size_t)N * 4);

    const int tb = 256;
    hipMemsetAsync(deg, 0, (size_t)N * 4, stream);
    count_deg_kernel<<<(E + tb - 1) / tb, tb, 0, stream>>>(dst, deg, E);

    int B = (N + 255) / 256;
    block_sum_kernel<<<B, 256, 0, stream>>>(deg, blockSums, N);
    scan_sums_kernel<<<1, 1024, 0, stream>>>(blockSums, row_ptr + N, B);
    write_rowptr_kernel<<<B, 256, 0, stream>>>(deg, blockSums, row_ptr, cursor, N);

    scatter_kernel<<<(E + tb - 1) / tb, tb, 0, stream>>>(src, dst, cursor, src_idx, E);

    int total8 = N * 8;
    cvt_x_kernel<<<(total8 + tb - 1) / tb, tb, 0, stream>>>(x, x16, total8);

    int nodeBlocks = (N + 3) / 4;   // one wave per node, 4 waves/block
    agg_mean8_kernel<<<nodeBlocks, tb, 0, stream>>>(x16, row_ptr, src_idx, hA, N);
    agg_mean8_kernel<<<nodeBlocks, tb, 0, stream>>>(hA,  row_ptr, src_idx, hB, N);
    agg_mean8_kernel<<<nodeBlocks, tb, 0, stream>>>(hB,  row_ptr, src_idx, hC, N);

    xform1_kernel<<<nodeBlocks, tb, 0, stream>>>(x, hA, hB, hC, W_lin1, W_att1,
                                                 z1, a1, a2, N);
    agg_conv64_kernel<<<nodeBlocks, tb, 0, stream>>>(z1, a1, a2, b_att1, row_ptr, src_idx,
                                                     h1c, N);
    xform2_kernel<<<nodeBlocks, tb, 0, stream>>>(h1c, W_lin2, W_att2, z2, a1b, a2b, N);
    agg_conv32_kernel<<<nodeBlocks, tb, 0, stream>>>(z2, a1b, a2b, b_att2, row_ptr, src_idx,
                                                     out, N);
}

// Round 8
// 305.354 us; speedup vs baseline: 1.3261x; 1.0356x over previous
//
#include <hip/hip_runtime.h>

// DeformableGCN: 3x mean-smoothing + 2x attention-weighted GCN conv.
// CSR-by-dst, wave-per-dst-node gathers, separate node-level transforms.
// R7: 8-lane-group half8/float4 gathers, branchless predication.
// R8: (a) CSR build via LDS-staged 2-pass bin-sort (dense writes only; no
// random global scatter, no count_deg kernel); (b) row starts aligned to 4
// entries so gather kernels load 4 edge indices as one ushort4 (8B).

typedef __attribute__((ext_vector_type(8))) _Float16 half8;

#define CHUNK 4096

// ---- pass A: bin edges into partition-sorted chunks (dense writes) ----
// Also accumulates global per-node degree (replaces count_deg).
__global__ void binA_kernel(const int* __restrict__ src, const int* __restrict__ dst,
                            int* __restrict__ deg, unsigned int* __restrict__ packed,
                            int* __restrict__ offs, int E) {
    __shared__ int cnt[256];
    __shared__ int pref[256];
    __shared__ int cur[256];
    __shared__ unsigned int stage[CHUNK];
    int t = threadIdx.x;
    int base = blockIdx.x * CHUNK;
    int len = E - base; if (len > CHUNK) len = CHUNK;
    cnt[t] = 0;
    __syncthreads();
    for (int i = t; i < len; i += 256) {
        int d = dst[base + i];
        atomicAdd(&deg[d], 1);
        atomicAdd(&cnt[d >> 8], 1);
    }
    __syncthreads();
    // inclusive scan of cnt -> pref
    int v = cnt[t];
    pref[t] = v;
    __syncthreads();
    for (int off = 1; off < 256; off <<= 1) {
        int u = (t >= off) ? pref[t - off] : 0;
        __syncthreads();
        pref[t] += u;
        __syncthreads();
    }
    int excl = pref[t] - v;
    cur[t] = excl;
    offs[blockIdx.x * 257 + t] = excl;
    if (t == 255) offs[blockIdx.x * 257 + 256] = pref[255];
    __syncthreads();
    for (int i = t; i < len; i += 256) {
        int s = src[base + i], d = dst[base + i];
        int pos = atomicAdd(&cur[d >> 8], 1);
        stage[pos] = (unsigned int)s | ((unsigned int)d << 16);
    }
    __syncthreads();
    for (int i = t; i < len; i += 256) packed[base + i] = stage[i];
}

// ---- scan over 4-aligned degrees -> aligned row starts ----
__global__ void block_sum_kernel(const int* __restrict__ deg, int* __restrict__ blockSums, int N) {
    __shared__ int sh[256];
    int i = blockIdx.x * 256 + threadIdx.x;
    int v = (i < N) ? ((deg[i] + 3) & ~3) : 0;
    sh[threadIdx.x] = v;
    __syncthreads();
    for (int off = 128; off > 0; off >>= 1) {
        if (threadIdx.x < off) sh[threadIdx.x] += sh[threadIdx.x + off];
        __syncthreads();
    }
    if (threadIdx.x == 0) blockSums[blockIdx.x] = sh[0];
}

__global__ void scan_sums_kernel(int* __restrict__ blockSums, int* __restrict__ row_ptr_N, int B) {
    __shared__ int sh[1024];
    int t = threadIdx.x;
    int v = (t < B) ? blockSums[t] : 0;
    sh[t] = v;
    __syncthreads();
    for (int off = 1; off < 1024; off <<= 1) {
        int u = (t >= off) ? sh[t - off] : 0;
        __syncthreads();
        sh[t] += u;
        __syncthreads();
    }
    if (t < B) blockSums[t] = sh[t] - v;
    if (t == 1023) row_ptr_N[0] = sh[1023];
}

__global__ void write_rowptr_kernel(const int* __restrict__ deg, const int* __restrict__ blockOffs,
                                    int* __restrict__ row_ptr, int N) {
    __shared__ int sh[256];
    int i = blockIdx.x * 256 + threadIdx.x;
    int v = (i < N) ? ((deg[i] + 3) & ~3) : 0;
    sh[threadIdx.x] = v;
    __syncthreads();
    for (int off = 1; off < 256; off <<= 1) {
        int u = (threadIdx.x >= off) ? sh[threadIdx.x - off] : 0;
        __syncthreads();
        sh[threadIdx.x] += u;
        __syncthreads();
    }
    if (i < N) row_ptr[i] = blockOffs[blockIdx.x] + sh[threadIdx.x] - v;
}

// ---- pass B: one block per partition; scatter within an ~8KB window ----
__global__ void binB_kernel(const unsigned int* __restrict__ packed, const int* __restrict__ offs,
                            const int* __restrict__ row_ptr, unsigned short* __restrict__ src_idx,
                            int nChunks) {
    __shared__ int cur[256];
    int t = threadIdx.x;
    int p = blockIdx.x;
    cur[t] = 0;
    __syncthreads();
    for (int c = t; c < nChunks; c += 256) {
        const int* oc = offs + c * 257;
        int o0 = oc[p], o1 = oc[p + 1];
        const unsigned int* pk = packed + (size_t)c * CHUNK;
        for (int i = o0; i < o1; ++i) {
            unsigned int pr = pk[i];
            int d = pr >> 16;
            int slot = atomicAdd(&cur[d & 255], 1);
            src_idx[row_ptr[d] + slot] = (unsigned short)(pr & 0xffffu);
        }
    }
}

// x (fp32) -> x16 (fp16), one half8 per thread.
__global__ void cvt_x_kernel(const float* __restrict__ x, _Float16* __restrict__ x16, int total8) {
    int i = blockIdx.x * blockDim.x + threadIdx.x;
    if (i >= total8) return;
    float4 v0 = ((const float4*)x)[2 * i];
    float4 v1 = ((const float4*)x)[2 * i + 1];
    half8 o;
    o[0] = (_Float16)v0.x; o[1] = (_Float16)v0.y; o[2] = (_Float16)v0.z; o[3] = (_Float16)v0.w;
    o[4] = (_Float16)v1.x; o[5] = (_Float16)v1.y; o[6] = (_Float16)v1.z; o[7] = (_Float16)v1.w;
    ((half8*)x16)[i] = o;
}

// Mean aggregation over fp16 rows (128B = 8 lanes x half8). One wave per
// node, 8 groups x 8 lanes, ushort4 index load, 4 predicated slots/group.
__global__ void agg_mean8_kernel(const _Float16* __restrict__ h, const int* __restrict__ row_ptr,
                                 const int* __restrict__ degp,
                                 const unsigned short* __restrict__ src_idx,
                                 _Float16* __restrict__ h_out, int N) {
    int wid = (blockIdx.x * blockDim.x + threadIdx.x) >> 6;
    int lane = threadIdx.x & 63;
    if (wid >= N) return;
    int beg = row_ptr[wid];
    int dgr = degp[wid];
    int end = beg + dgr;
    int j = lane >> 3, f = lane & 7;
    const uint4* rowp = (const uint4*)h;
    float acc[8];
    #pragma unroll
    for (int q = 0; q < 8; ++q) acc[q] = 0.f;
    for (int base = beg + 4 * j; base < end; base += 32) {
        ushort4 i4 = *(const ushort4*)(src_idx + base);   // base 4-aligned
        unsigned short ss[4] = {i4.x, i4.y, i4.z, i4.w};
        #pragma unroll
        for (int k = 0; k < 4; ++k) {
            int e = base + k;
            int s = ss[k];
            uint4 raw = rowp[(size_t)s * 8 + f];
            if (e >= end) { raw.x = 0u; raw.y = 0u; raw.z = 0u; raw.w = 0u; }
            half8 v = *(half8*)&raw;
            #pragma unroll
            for (int q = 0; q < 8; ++q) acc[q] += (float)v[q];
        }
    }
    #pragma unroll
    for (int q = 0; q < 8; ++q) {
        acc[q] += __shfl_down(acc[q], 32, 64);
        acc[q] += __shfl_down(acc[q], 16, 64);
        acc[q] += __shfl_down(acc[q], 8, 64);
    }
    if (lane < 8) {
        float inv = dgr > 0 ? 1.f / (float)dgr : 0.f;
        half8 o;
        #pragma unroll
        for (int q = 0; q < 8; ++q) o[q] = (_Float16)(acc[q] * inv);
        *((half8*)h_out + (size_t)wid * 8 + lane) = o;
    }
}

// Conv1 transform: xs = (x+h1+h2+h3)/4. z1 = xs@W_lin1 (fp16), a1/a2 dots.
__global__ void xform1_kernel(const float* __restrict__ x, const _Float16* __restrict__ hA,
                              const _Float16* __restrict__ hB, const _Float16* __restrict__ hC,
                              const float* __restrict__ W_lin1, const float* __restrict__ W_att1,
                              _Float16* __restrict__ z1, float* __restrict__ a1,
                              float* __restrict__ a2, int N) {
    __shared__ float row[4][64];
    int wib = threadIdx.x >> 6;
    int lane = threadIdx.x & 63;
    int n = blockIdx.x * 4 + wib;
    int nc = n < N ? n : N - 1;
    size_t idx = (size_t)nc * 64 + lane;
    float xv = (x[idx] + (float)hA[idx] + (float)hB[idx] + (float)hC[idx]) * 0.25f;
    row[wib][lane] = xv;
    __syncthreads();
    float p1 = xv * W_att1[lane];
    float p2 = xv * W_att1[64 + lane];
    for (int off = 32; off > 0; off >>= 1) {
        p1 += __shfl_down(p1, off, 64);
        p2 += __shfl_down(p2, off, 64);
    }
    float acc = 0.f;
    #pragma unroll
    for (int k = 0; k < 64; ++k) acc += row[wib][k] * W_lin1[k * 64 + lane];
    if (n < N) {
        z1[(size_t)n * 64 + lane] = (_Float16)acc;
        if (lane == 0) { a1[n] = p1; a2[n] = p2; }
    }
}

__global__ void xform2_kernel(const float* __restrict__ h1, const float* __restrict__ W_lin2,
                              const float* __restrict__ W_att2,
                              float* __restrict__ z2, float* __restrict__ a1, float* __restrict__ a2,
                              int N) {
    __shared__ float row[4][64];
    int wib = threadIdx.x >> 6;
    int lane = threadIdx.x & 63;
    int n = blockIdx.x * 4 + wib;
    int nc = n < N ? n : N - 1;
    float hv = h1[(size_t)nc * 64 + lane];
    row[wib][lane] = hv;
    __syncthreads();
    float p1 = hv * W_att2[lane];
    float p2 = hv * W_att2[64 + lane];
    for (int off = 32; off > 0; off >>= 1) {
        p1 += __shfl_down(p1, off, 64);
        p2 += __shfl_down(p2, off, 64);
    }
    float acc = 0.f;
    if (lane < 32) {
        #pragma unroll
        for (int k = 0; k < 64; ++k) acc += row[wib][k] * W_lin2[k * 32 + lane];
    }
    if (n < N) {
        if (lane < 32) z2[(size_t)n * 32 + lane] = acc;
        if (lane == 0) { a1[n] = p1; a2[n] = p2; }
    }
}

// Conv1 aggregation: fp16 z1 rows, 8-lane groups, ushort4 index loads,
// per-edge leaky score, relu -> fp32 out.
__global__ void agg_conv64_kernel(const _Float16* __restrict__ z, const float* __restrict__ a1v,
                                  const float* __restrict__ a2v, const float* __restrict__ b_att,
                                  const int* __restrict__ row_ptr, const int* __restrict__ degp,
                                  const unsigned short* __restrict__ src_idx,
                                  float* __restrict__ outp, int N) {
    int wid = (blockIdx.x * blockDim.x + threadIdx.x) >> 6;
    int lane = threadIdx.x & 63;
    if (wid >= N) return;
    float ad = a2v[wid] + b_att[0];
    int beg = row_ptr[wid];
    int end = beg + degp[wid];
    int j = lane >> 3, f = lane & 7;
    const uint4* rowp = (const uint4*)z;
    float acc[8];
    #pragma unroll
    for (int q = 0; q < 8; ++q) acc[q] = 0.f;
    for (int base = beg + 4 * j; base < end; base += 32) {
        ushort4 i4 = *(const ushort4*)(src_idx + base);
        unsigned short ss[4] = {i4.x, i4.y, i4.z, i4.w};
        #pragma unroll
        for (int k = 0; k < 4; ++k) {
            int e = base + k;
            int s = ss[k];
            float sc = a1v[s] + ad;
            sc = sc > 0.f ? sc : 0.01f * sc;
            uint4 raw = rowp[(size_t)s * 8 + f];
            if (e >= end) { raw.x = 0u; raw.y = 0u; raw.z = 0u; raw.w = 0u; }
            half8 v = *(half8*)&raw;
            #pragma unroll
            for (int q = 0; q < 8; ++q) acc[q] += sc * (float)v[q];
        }
    }
    #pragma unroll
    for (int q = 0; q < 8; ++q) {
        acc[q] += __shfl_down(acc[q], 32, 64);
        acc[q] += __shfl_down(acc[q], 16, 64);
        acc[q] += __shfl_down(acc[q], 8, 64);
    }
    if (lane < 8) {
        float4 o0, o1;
        o0.x = fmaxf(acc[0], 0.f); o0.y = fmaxf(acc[1], 0.f);
        o0.z = fmaxf(acc[2], 0.f); o0.w = fmaxf(acc[3], 0.f);
        o1.x = fmaxf(acc[4], 0.f); o1.y = fmaxf(acc[5], 0.f);
        o1.z = fmaxf(acc[6], 0.f); o1.w = fmaxf(acc[7], 0.f);
        float4* op = (float4*)(outp + (size_t)wid * 64 + lane * 8);
        op[0] = o0; op[1] = o1;
    }
}

// Conv2 aggregation: fp32 z2 rows (128B = 8 lanes x float4), ushort4 index
// loads, branchless predication.
__global__ void agg_conv32_kernel(const float* __restrict__ z, const float* __restrict__ a1v,
                                  const float* __restrict__ a2v, const float* __restrict__ b_att,
                                  const int* __restrict__ row_ptr, const int* __restrict__ degp,
                                  const unsigned short* __restrict__ src_idx,
                                  float* __restrict__ outp, int N) {
    int wid = (blockIdx.x * blockDim.x + threadIdx.x) >> 6;
    int lane = threadIdx.x & 63;
    if (wid >= N) return;
    float ad = a2v[wid] + b_att[0];
    int beg = row_ptr[wid];
    int end = beg + degp[wid];
    int j = lane >> 3, f = lane & 7;
    const float4* rowp = (const float4*)z;
    float ax = 0.f, ay = 0.f, az = 0.f, aw = 0.f;
    for (int base = beg + 4 * j; base < end; base += 32) {
        ushort4 i4 = *(const ushort4*)(src_idx + base);
        unsigned short ss[4] = {i4.x, i4.y, i4.z, i4.w};
        #pragma unroll
        for (int k = 0; k < 4; ++k) {
            int e = base + k;
            int s = ss[k];
            float sc = a1v[s] + ad;
            sc = sc > 0.f ? sc : 0.01f * sc;
            if (e >= end) sc = 0.f;
            float4 v = rowp[(size_t)s * 8 + f];
            ax += sc * v.x; ay += sc * v.y; az += sc * v.z; aw += sc * v.w;
        }
    }
    ax += __shfl_down(ax, 32, 64); ay += __shfl_down(ay, 32, 64);
    az += __shfl_down(az, 32, 64); aw += __shfl_down(aw, 32, 64);
    ax += __shfl_down(ax, 16, 64); ay += __shfl_down(ay, 16, 64);
    az += __shfl_down(az, 16, 64); aw += __shfl_down(aw, 16, 64);
    ax += __shfl_down(ax, 8, 64);  ay += __shfl_down(ay, 8, 64);
    az += __shfl_down(az, 8, 64);  aw += __shfl_down(aw, 8, 64);
    if (lane < 8) {
        float4 o; o.x = ax; o.y = ay; o.z = az; o.w = aw;
        *((float4*)(outp + (size_t)wid * 32) + lane) = o;
    }
}

extern "C" void kernel_launch(void* const* d_in, const int* in_sizes, int n_in,
                              void* d_out, int out_size, void* d_ws, size_t ws_size,
                              hipStream_t stream) {
    const float* x      = (const float*)d_in[0];
    const int*   ei     = (const int*)d_in[1];
    const float* W_att1 = (const float*)d_in[2];
    const float* b_att1 = (const float*)d_in[3];
    const float* W_lin1 = (const float*)d_in[4];
    const float* W_att2 = (const float*)d_in[5];
    const float* b_att2 = (const float*)d_in[6];
    const float* W_lin2 = (const float*)d_in[7];
    float* out = (float*)d_out;

    int N = in_sizes[0] / 64;   // 50000 (< 65536, required for u16 indices)
    int E = in_sizes[1] / 2;
    const int* src = ei;
    const int* dst = ei + E;
    int nChunks = (E + CHUNK - 1) / CHUNK;   // 196
    int nPart   = (N + 255) >> 8;            // 196

    char* ws = (char*)d_ws;
    size_t off = 0;
    auto alloc = [&](size_t bytes) -> void* {
        void* p = ws + off;
        off += (bytes + 255) & ~(size_t)255;
        return p;
    };
    int*            deg       = (int*)alloc((size_t)N * 4);
    int*            row_ptr   = (int*)alloc((size_t)(N + 1) * 4);
    unsigned short* src_idx   = (unsigned short*)alloc(((size_t)E + 4 * N) * 2);
    int*            blockSums = (int*)alloc((size_t)1024 * 4);
    unsigned int*   packed    = (unsigned int*)alloc((size_t)nChunks * CHUNK * 4);
    int*            offs      = (int*)alloc((size_t)nChunks * 257 * 4);
    _Float16* x16 = (_Float16*)alloc((size_t)N * 64 * 2);
    _Float16* hA  = (_Float16*)alloc((size_t)N * 64 * 2);
    _Float16* hB  = (_Float16*)alloc((size_t)N * 64 * 2);
    _Float16* hC  = (_Float16*)alloc((size_t)N * 64 * 2);
    _Float16* z1  = (_Float16*)alloc((size_t)N * 64 * 2);
    float* h1c = (float*)alloc((size_t)N * 64 * 4);
    float* z2  = (float*)alloc((size_t)N * 32 * 4);
    float* a1  = (float*)alloc((size_t)N * 4);
    float* a2  = (float*)alloc((size_t)N * 4);
    float* a1b = (float*)alloc((size_t)N * 4);
    float* a2b = (float*)alloc((size_t)N * 4);

    const int tb = 256;
    hipMemsetAsync(deg, 0, (size_t)N * 4, stream);

    binA_kernel<<<nChunks, 256, 0, stream>>>(src, dst, deg, packed, offs, E);

    int B = (N + 255) / 256;
    block_sum_kernel<<<B, 256, 0, stream>>>(deg, blockSums, N);
    scan_sums_kernel<<<1, 1024, 0, stream>>>(blockSums, row_ptr + N, B);
    write_rowptr_kernel<<<B, 256, 0, stream>>>(deg, blockSums, row_ptr, N);

    binB_kernel<<<nPart, 256, 0, stream>>>(packed, offs, row_ptr, src_idx, nChunks);

    int total8 = N * 8;
    cvt_x_kernel<<<(total8 + tb - 1) / tb, tb, 0, stream>>>(x, x16, total8);

    int nodeBlocks = (N + 3) / 4;   // one wave per node, 4 waves/block
    agg_mean8_kernel<<<nodeBlocks, tb, 0, stream>>>(x16, row_ptr, deg, src_idx, hA, N);
    agg_mean8_kernel<<<nodeBlocks, tb, 0, stream>>>(hA,  row_ptr, deg, src_idx, hB, N);
    agg_mean8_kernel<<<nodeBlocks, tb, 0, stream>>>(hB,  row_ptr, deg, src_idx, hC, N);

    xform1_kernel<<<nodeBlocks, tb, 0, stream>>>(x, hA, hB, hC, W_lin1, W_att1,
                                                 z1, a1, a2, N);
    agg_conv64_kernel<<<nodeBlocks, tb, 0, stream>>>(z1, a1, a2, b_att1, row_ptr, deg, src_idx,
                                                     h1c, N);
    xform2_kernel<<<nodeBlocks, tb, 0, stream>>>(h1c, W_lin2, W_att2, z2, a1b, a2b, N);
    agg_conv32_kernel<<<nodeBlocks, tb, 0, stream>>>(z2, a1b, a2b, b_att2, row_ptr, deg, src_idx,
                                                     out, N);
}

// Round 9
// 271.939 us; speedup vs baseline: 1.4890x; 1.1229x over previous
//
#include <hip/hip_runtime.h>

// DeformableGCN: 3x mean-smoothing + 2x attention-weighted GCN conv.
// CSR-by-dst, wave-per-dst-node gathers, separate node-level transforms.
// R7: 8-lane-group half8/float4 gathers, branchless predication.
// R8: LDS-staged 2-pass bin-sort CSR build; ushort4 index loads (4-aligned rows).
// R9: partition-parallel CSR build — binA (2048-edge chunks, no global
// atomics) -> binB_count (dense deg via per-partition LDS counters) ->
// part_scan (196 totals) -> binB_scatter (dense row_ptr + windowed scatter).
// Removes 800k global atomics, 3 scan kernels, and the deg memset.

typedef __attribute__((ext_vector_type(8))) _Float16 half8;

#define CHUNK 2048

// ---- pass A: bin edges into partition-sorted chunks (dense writes) ----
__global__ void binA_kernel(const int* __restrict__ src, const int* __restrict__ dst,
                            unsigned int* __restrict__ packed, int* __restrict__ offs, int E) {
    __shared__ int cnt[256];
    __shared__ int pref[256];
    __shared__ int cur[256];
    __shared__ unsigned int stage[CHUNK];
    int t = threadIdx.x;
    int base = blockIdx.x * CHUNK;
    int len = E - base; if (len > CHUNK) len = CHUNK;
    cnt[t] = 0;
    __syncthreads();
    for (int i = t; i < len; i += 256) atomicAdd(&cnt[dst[base + i] >> 8], 1);
    __syncthreads();
    int v = cnt[t];
    pref[t] = v;
    __syncthreads();
    for (int off = 1; off < 256; off <<= 1) {
        int u = (t >= off) ? pref[t - off] : 0;
        __syncthreads();
        pref[t] += u;
        __syncthreads();
    }
    int excl = pref[t] - v;
    cur[t] = excl;
    offs[blockIdx.x * 257 + t] = excl;
    if (t == 255) offs[blockIdx.x * 257 + 256] = pref[255];
    __syncthreads();
    for (int i = t; i < len; i += 256) {
        int s = src[base + i], d = dst[base + i];
        int pos = atomicAdd(&cur[d >> 8], 1);
        stage[pos] = (unsigned int)s | ((unsigned int)d << 16);
    }
    __syncthreads();
    for (int i = t; i < len; i += 256) packed[base + i] = stage[i];
}

// ---- per-partition degree count: dense deg write + aligned total ----
__global__ void binB_count_kernel(const unsigned int* __restrict__ packed,
                                  const int* __restrict__ offs,
                                  int* __restrict__ deg, int* __restrict__ partTot,
                                  int nChunks, int N) {
    __shared__ int cnt[256];
    __shared__ int red[256];
    int t = threadIdx.x;
    int p = blockIdx.x;
    cnt[t] = 0;
    __syncthreads();
    for (int c = t; c < nChunks; c += 256) {
        const int* oc = offs + c * 257;
        int o0 = oc[p], o1 = oc[p + 1];
        const unsigned int* pk = packed + (size_t)c * CHUNK;
        for (int i = o0; i < o1; ++i) atomicAdd(&cnt[(pk[i] >> 16) & 255], 1);
    }
    __syncthreads();
    int node = p * 256 + t;
    int c = cnt[t];
    if (node < N) deg[node] = c;
    red[t] = (c + 3) & ~3;
    __syncthreads();
    for (int off = 128; off > 0; off >>= 1) {
        if (t < off) red[t] += red[t + off];
        __syncthreads();
    }
    if (t == 0) partTot[p] = red[0];
}

// ---- scan over partition totals (nPart <= 256) ----
__global__ void part_scan_kernel(const int* __restrict__ partTot, int* __restrict__ partBase,
                                 int nPart) {
    __shared__ int sh[256];
    int t = threadIdx.x;
    int v = (t < nPart) ? partTot[t] : 0;
    sh[t] = v;
    __syncthreads();
    for (int off = 1; off < 256; off <<= 1) {
        int u = (t >= off) ? sh[t - off] : 0;
        __syncthreads();
        sh[t] += u;
        __syncthreads();
    }
    if (t < nPart) partBase[t] = sh[t] - v;
}

// ---- per-partition scatter: dense row_ptr + windowed src_idx writes ----
__global__ void binB_scatter_kernel(const unsigned int* __restrict__ packed,
                                    const int* __restrict__ offs, const int* __restrict__ deg,
                                    const int* __restrict__ partBase, int* __restrict__ row_ptr,
                                    unsigned short* __restrict__ src_idx, int nChunks, int N) {
    __shared__ int pref[256];
    __shared__ int cur[256];
    int t = threadIdx.x;
    int p = blockIdx.x;
    int node = p * 256 + t;
    int d = (node < N) ? deg[node] : 0;
    int a = (d + 3) & ~3;
    pref[t] = a;
    __syncthreads();
    for (int off = 1; off < 256; off <<= 1) {
        int u = (t >= off) ? pref[t - off] : 0;
        __syncthreads();
        pref[t] += u;
        __syncthreads();
    }
    int rp = partBase[p] + pref[t] - a;
    if (node < N) row_ptr[node] = rp;
    cur[t] = rp;
    __syncthreads();
    for (int c = t; c < nChunks; c += 256) {
        const int* oc = offs + c * 257;
        int o0 = oc[p], o1 = oc[p + 1];
        const unsigned int* pk = packed + (size_t)c * CHUNK;
        for (int i = o0; i < o1; ++i) {
            unsigned int pr = pk[i];
            int ln = (pr >> 16) & 255;
            int slot = atomicAdd(&cur[ln], 1);
            src_idx[slot] = (unsigned short)(pr & 0xffffu);
        }
    }
}

// x (fp32) -> x16 (fp16), one half8 per thread.
__global__ void cvt_x_kernel(const float* __restrict__ x, _Float16* __restrict__ x16, int total8) {
    int i = blockIdx.x * blockDim.x + threadIdx.x;
    if (i >= total8) return;
    float4 v0 = ((const float4*)x)[2 * i];
    float4 v1 = ((const float4*)x)[2 * i + 1];
    half8 o;
    o[0] = (_Float16)v0.x; o[1] = (_Float16)v0.y; o[2] = (_Float16)v0.z; o[3] = (_Float16)v0.w;
    o[4] = (_Float16)v1.x; o[5] = (_Float16)v1.y; o[6] = (_Float16)v1.z; o[7] = (_Float16)v1.w;
    ((half8*)x16)[i] = o;
}

// Mean aggregation over fp16 rows (128B = 8 lanes x half8). One wave per
// node, 8 groups x 8 lanes, ushort4 index load, 4 predicated slots/group.
__global__ void agg_mean8_kernel(const _Float16* __restrict__ h, const int* __restrict__ row_ptr,
                                 const int* __restrict__ degp,
                                 const unsigned short* __restrict__ src_idx,
                                 _Float16* __restrict__ h_out, int N) {
    int wid = (blockIdx.x * blockDim.x + threadIdx.x) >> 6;
    int lane = threadIdx.x & 63;
    if (wid >= N) return;
    int beg = row_ptr[wid];
    int dgr = degp[wid];
    int end = beg + dgr;
    int j = lane >> 3, f = lane & 7;
    const uint4* rowp = (const uint4*)h;
    float acc[8];
    #pragma unroll
    for (int q = 0; q < 8; ++q) acc[q] = 0.f;
    for (int base = beg + 4 * j; base < end; base += 32) {
        ushort4 i4 = *(const ushort4*)(src_idx + base);   // base 4-aligned
        unsigned short ss[4] = {i4.x, i4.y, i4.z, i4.w};
        #pragma unroll
        for (int k = 0; k < 4; ++k) {
            int e = base + k;
            int s = ss[k];
            uint4 raw = rowp[(size_t)s * 8 + f];
            if (e >= end) { raw.x = 0u; raw.y = 0u; raw.z = 0u; raw.w = 0u; }
            half8 v = *(half8*)&raw;
            #pragma unroll
            for (int q = 0; q < 8; ++q) acc[q] += (float)v[q];
        }
    }
    #pragma unroll
    for (int q = 0; q < 8; ++q) {
        acc[q] += __shfl_down(acc[q], 32, 64);
        acc[q] += __shfl_down(acc[q], 16, 64);
        acc[q] += __shfl_down(acc[q], 8, 64);
    }
    if (lane < 8) {
        float inv = dgr > 0 ? 1.f / (float)dgr : 0.f;
        half8 o;
        #pragma unroll
        for (int q = 0; q < 8; ++q) o[q] = (_Float16)(acc[q] * inv);
        *((half8*)h_out + (size_t)wid * 8 + lane) = o;
    }
}

// Conv1 transform: xs = (x+h1+h2+h3)/4. z1 = xs@W_lin1 (fp16), a1/a2 dots.
__global__ void xform1_kernel(const float* __restrict__ x, const _Float16* __restrict__ hA,
                              const _Float16* __restrict__ hB, const _Float16* __restrict__ hC,
                              const float* __restrict__ W_lin1, const float* __restrict__ W_att1,
                              _Float16* __restrict__ z1, float* __restrict__ a1,
                              float* __restrict__ a2, int N) {
    __shared__ float row[4][64];
    int wib = threadIdx.x >> 6;
    int lane = threadIdx.x & 63;
    int n = blockIdx.x * 4 + wib;
    int nc = n < N ? n : N - 1;
    size_t idx = (size_t)nc * 64 + lane;
    float xv = (x[idx] + (float)hA[idx] + (float)hB[idx] + (float)hC[idx]) * 0.25f;
    row[wib][lane] = xv;
    __syncthreads();
    float p1 = xv * W_att1[lane];
    float p2 = xv * W_att1[64 + lane];
    for (int off = 32; off > 0; off >>= 1) {
        p1 += __shfl_down(p1, off, 64);
        p2 += __shfl_down(p2, off, 64);
    }
    float acc = 0.f;
    #pragma unroll
    for (int k = 0; k < 64; ++k) acc += row[wib][k] * W_lin1[k * 64 + lane];
    if (n < N) {
        z1[(size_t)n * 64 + lane] = (_Float16)acc;
        if (lane == 0) { a1[n] = p1; a2[n] = p2; }
    }
}

__global__ void xform2_kernel(const float* __restrict__ h1, const float* __restrict__ W_lin2,
                              const float* __restrict__ W_att2,
                              float* __restrict__ z2, float* __restrict__ a1, float* __restrict__ a2,
                              int N) {
    __shared__ float row[4][64];
    int wib = threadIdx.x >> 6;
    int lane = threadIdx.x & 63;
    int n = blockIdx.x * 4 + wib;
    int nc = n < N ? n : N - 1;
    float hv = h1[(size_t)nc * 64 + lane];
    row[wib][lane] = hv;
    __syncthreads();
    float p1 = hv * W_att2[lane];
    float p2 = hv * W_att2[64 + lane];
    for (int off = 32; off > 0; off >>= 1) {
        p1 += __shfl_down(p1, off, 64);
        p2 += __shfl_down(p2, off, 64);
    }
    float acc = 0.f;
    if (lane < 32) {
        #pragma unroll
        for (int k = 0; k < 64; ++k) acc += row[wib][k] * W_lin2[k * 32 + lane];
    }
    if (n < N) {
        if (lane < 32) z2[(size_t)n * 32 + lane] = acc;
        if (lane == 0) { a1[n] = p1; a2[n] = p2; }
    }
}

// Conv1 aggregation: fp16 z1 rows, 8-lane groups, ushort4 index loads,
// per-edge leaky score, relu -> fp32 out.
__global__ void agg_conv64_kernel(const _Float16* __restrict__ z, const float* __restrict__ a1v,
                                  const float* __restrict__ a2v, const float* __restrict__ b_att,
                                  const int* __restrict__ row_ptr, const int* __restrict__ degp,
                                  const unsigned short* __restrict__ src_idx,
                                  float* __restrict__ outp, int N) {
    int wid = (blockIdx.x * blockDim.x + threadIdx.x) >> 6;
    int lane = threadIdx.x & 63;
    if (wid >= N) return;
    float ad = a2v[wid] + b_att[0];
    int beg = row_ptr[wid];
    int end = beg + degp[wid];
    int j = lane >> 3, f = lane & 7;
    const uint4* rowp = (const uint4*)z;
    float acc[8];
    #pragma unroll
    for (int q = 0; q < 8; ++q) acc[q] = 0.f;
    for (int base = beg + 4 * j; base < end; base += 32) {
        ushort4 i4 = *(const ushort4*)(src_idx + base);
        unsigned short ss[4] = {i4.x, i4.y, i4.z, i4.w};
        #pragma unroll
        for (int k = 0; k < 4; ++k) {
            int e = base + k;
            int s = ss[k];
            float sc = a1v[s] + ad;
            sc = sc > 0.f ? sc : 0.01f * sc;
            uint4 raw = rowp[(size_t)s * 8 + f];
            if (e >= end) { raw.x = 0u; raw.y = 0u; raw.z = 0u; raw.w = 0u; }
            half8 v = *(half8*)&raw;
            #pragma unroll
            for (int q = 0; q < 8; ++q) acc[q] += sc * (float)v[q];
        }
    }
    #pragma unroll
    for (int q = 0; q < 8; ++q) {
        acc[q] += __shfl_down(acc[q], 32, 64);
        acc[q] += __shfl_down(acc[q], 16, 64);
        acc[q] += __shfl_down(acc[q], 8, 64);
    }
    if (lane < 8) {
        float4 o0, o1;
        o0.x = fmaxf(acc[0], 0.f); o0.y = fmaxf(acc[1], 0.f);
        o0.z = fmaxf(acc[2], 0.f); o0.w = fmaxf(acc[3], 0.f);
        o1.x = fmaxf(acc[4], 0.f); o1.y = fmaxf(acc[5], 0.f);
        o1.z = fmaxf(acc[6], 0.f); o1.w = fmaxf(acc[7], 0.f);
        float4* op = (float4*)(outp + (size_t)wid * 64 + lane * 8);
        op[0] = o0; op[1] = o1;
    }
}

// Conv2 aggregation: fp32 z2 rows (128B = 8 lanes x float4), ushort4 index
// loads, branchless predication.
__global__ void agg_conv32_kernel(const float* __restrict__ z, const float* __restrict__ a1v,
                                  const float* __restrict__ a2v, const float* __restrict__ b_att,
                                  const int* __restrict__ row_ptr, const int* __restrict__ degp,
                                  const unsigned short* __restrict__ src_idx,
                                  float* __restrict__ outp, int N) {
    int wid = (blockIdx.x * blockDim.x + threadIdx.x) >> 6;
    int lane = threadIdx.x & 63;
    if (wid >= N) return;
    float ad = a2v[wid] + b_att[0];
    int beg = row_ptr[wid];
    int end = beg + degp[wid];
    int j = lane >> 3, f = lane & 7;
    const float4* rowp = (const float4*)z;
    float ax = 0.f, ay = 0.f, az = 0.f, aw = 0.f;
    for (int base = beg + 4 * j; base < end; base += 32) {
        ushort4 i4 = *(const ushort4*)(src_idx + base);
        unsigned short ss[4] = {i4.x, i4.y, i4.z, i4.w};
        #pragma unroll
        for (int k = 0; k < 4; ++k) {
            int e = base + k;
            int s = ss[k];
            float sc = a1v[s] + ad;
            sc = sc > 0.f ? sc : 0.01f * sc;
            if (e >= end) sc = 0.f;
            float4 v = rowp[(size_t)s * 8 + f];
            ax += sc * v.x; ay += sc * v.y; az += sc * v.z; aw += sc * v.w;
        }
    }
    ax += __shfl_down(ax, 32, 64); ay += __shfl_down(ay, 32, 64);
    az += __shfl_down(az, 32, 64); aw += __shfl_down(aw, 32, 64);
    ax += __shfl_down(ax, 16, 64); ay += __shfl_down(ay, 16, 64);
    az += __shfl_down(az, 16, 64); aw += __shfl_down(aw, 16, 64);
    ax += __shfl_down(ax, 8, 64);  ay += __shfl_down(ay, 8, 64);
    az += __shfl_down(az, 8, 64);  aw += __shfl_down(aw, 8, 64);
    if (lane < 8) {
        float4 o; o.x = ax; o.y = ay; o.z = az; o.w = aw;
        *((float4*)(outp + (size_t)wid * 32) + lane) = o;
    }
}

extern "C" void kernel_launch(void* const* d_in, const int* in_sizes, int n_in,
                              void* d_out, int out_size, void* d_ws, size_t ws_size,
                              hipStream_t stream) {
    const float* x      = (const float*)d_in[0];
    const int*   ei     = (const int*)d_in[1];
    const float* W_att1 = (const float*)d_in[2];
    const float* b_att1 = (const float*)d_in[3];
    const float* W_lin1 = (const float*)d_in[4];
    const float* W_att2 = (const float*)d_in[5];
    const float* b_att2 = (const float*)d_in[6];
    const float* W_lin2 = (const float*)d_in[7];
    float* out = (float*)d_out;

    int N = in_sizes[0] / 64;   // 50000 (< 65536, required for u16 indices)
    int E = in_sizes[1] / 2;
    const int* src = ei;
    const int* dst = ei + E;
    int nChunks = (E + CHUNK - 1) / CHUNK;   // 391
    int nPart   = (N + 255) >> 8;            // 196 (must be <= 256)

    char* ws = (char*)d_ws;
    size_t off = 0;
    auto alloc = [&](size_t bytes) -> void* {
        void* p = ws + off;
        off += (bytes + 255) & ~(size_t)255;
        return p;
    };
    int*            deg      = (int*)alloc((size_t)N * 4);
    int*            row_ptr  = (int*)alloc((size_t)N * 4);
    unsigned short* src_idx  = (unsigned short*)alloc(((size_t)E + 4 * N) * 2);
    unsigned int*   packed   = (unsigned int*)alloc((size_t)nChunks * CHUNK * 4);
    int*            offs     = (int*)alloc((size_t)nChunks * 257 * 4);
    int*            partTot  = (int*)alloc((size_t)256 * 4);
    int*            partBase = (int*)alloc((size_t)256 * 4);
    _Float16* x16 = (_Float16*)alloc((size_t)N * 64 * 2);
    _Float16* hA  = (_Float16*)alloc((size_t)N * 64 * 2);
    _Float16* hB  = (_Float16*)alloc((size_t)N * 64 * 2);
    _Float16* hC  = (_Float16*)alloc((size_t)N * 64 * 2);
    _Float16* z1  = (_Float16*)alloc((size_t)N * 64 * 2);
    float* h1c = (float*)alloc((size_t)N * 64 * 4);
    float* z2  = (float*)alloc((size_t)N * 32 * 4);
    float* a1  = (float*)alloc((size_t)N * 4);
    float* a2  = (float*)alloc((size_t)N * 4);
    float* a1b = (float*)alloc((size_t)N * 4);
    float* a2b = (float*)alloc((size_t)N * 4);

    const int tb = 256;

    binA_kernel<<<nChunks, 256, 0, stream>>>(src, dst, packed, offs, E);
    binB_count_kernel<<<nPart, 256, 0, stream>>>(packed, offs, deg, partTot, nChunks, N);
    part_scan_kernel<<<1, 256, 0, stream>>>(partTot, partBase, nPart);
    binB_scatter_kernel<<<nPart, 256, 0, stream>>>(packed, offs, deg, partBase, row_ptr,
                                                   src_idx, nChunks, N);

    int total8 = N * 8;
    cvt_x_kernel<<<(total8 + tb - 1) / tb, tb, 0, stream>>>(x, x16, total8);

    int nodeBlocks = (N + 3) / 4;   // one wave per node, 4 waves/block
    agg_mean8_kernel<<<nodeBlocks, tb, 0, stream>>>(x16, row_ptr, deg, src_idx, hA, N);
    agg_mean8_kernel<<<nodeBlocks, tb, 0, stream>>>(hA,  row_ptr, deg, src_idx, hB, N);
    agg_mean8_kernel<<<nodeBlocks, tb, 0, stream>>>(hB,  row_ptr, deg, src_idx, hC, N);

    xform1_kernel<<<nodeBlocks, tb, 0, stream>>>(x, hA, hB, hC, W_lin1, W_att1,
                                                 z1, a1, a2, N);
    agg_conv64_kernel<<<nodeBlocks, tb, 0, stream>>>(z1, a1, a2, b_att1, row_ptr, deg, src_idx,
                                                     h1c, N);
    xform2_kernel<<<nodeBlocks, tb, 0, stream>>>(h1c, W_lin2, W_att2, z2, a1b, a2b, N);
    agg_conv32_kernel<<<nodeBlocks, tb, 0, stream>>>(z2, a1b, a2b, b_att2, row_ptr, deg, src_idx,
                                                     out, N);
}

// Round 10
// 255.822 us; speedup vs baseline: 1.5828x; 1.0630x over previous
//
#include <hip/hip_runtime.h>

// DeformableGCN: 3x mean-smoothing + 2x attention-weighted GCN conv.
// CSR-by-dst, gathers, separate node-level transforms.
// R7: 8-lane-group half8/float4 gathers, branchless predication.
// R8: LDS bin-sort CSR; ushort4 index loads (4-aligned rows).
// R9: partition-parallel CSR build (binA/binB_count/part_scan/binB_scatter).
// R10: TWO nodes per wave in all gather passes — each 32-lane half owns one
// node (4 groups x 8 lanes x 4 slots = 16 edge slots/iter, matches mean
// degree 16). Fixes half-wave exec-mask idling; wave count halves.

typedef __attribute__((ext_vector_type(8))) _Float16 half8;

#define CHUNK 2048

// ---- pass A: bin edges into partition-sorted chunks (dense writes) ----
__global__ void binA_kernel(const int* __restrict__ src, const int* __restrict__ dst,
                            unsigned int* __restrict__ packed, int* __restrict__ offs, int E) {
    __shared__ int cnt[256];
    __shared__ int pref[256];
    __shared__ int cur[256];
    __shared__ unsigned int stage[CHUNK];
    int t = threadIdx.x;
    int base = blockIdx.x * CHUNK;
    int len = E - base; if (len > CHUNK) len = CHUNK;
    cnt[t] = 0;
    __syncthreads();
    for (int i = t; i < len; i += 256) atomicAdd(&cnt[dst[base + i] >> 8], 1);
    __syncthreads();
    int v = cnt[t];
    pref[t] = v;
    __syncthreads();
    for (int off = 1; off < 256; off <<= 1) {
        int u = (t >= off) ? pref[t - off] : 0;
        __syncthreads();
        pref[t] += u;
        __syncthreads();
    }
    int excl = pref[t] - v;
    cur[t] = excl;
    offs[blockIdx.x * 257 + t] = excl;
    if (t == 255) offs[blockIdx.x * 257 + 256] = pref[255];
    __syncthreads();
    for (int i = t; i < len; i += 256) {
        int s = src[base + i], d = dst[base + i];
        int pos = atomicAdd(&cur[d >> 8], 1);
        stage[pos] = (unsigned int)s | ((unsigned int)d << 16);
    }
    __syncthreads();
    for (int i = t; i < len; i += 256) packed[base + i] = stage[i];
}

// ---- per-partition degree count: dense deg write + aligned total ----
__global__ void binB_count_kernel(const unsigned int* __restrict__ packed,
                                  const int* __restrict__ offs,
                                  int* __restrict__ deg, int* __restrict__ partTot,
                                  int nChunks, int N) {
    __shared__ int cnt[256];
    __shared__ int red[256];
    int t = threadIdx.x;
    int p = blockIdx.x;
    cnt[t] = 0;
    __syncthreads();
    for (int c = t; c < nChunks; c += 256) {
        const int* oc = offs + c * 257;
        int o0 = oc[p], o1 = oc[p + 1];
        const unsigned int* pk = packed + (size_t)c * CHUNK;
        for (int i = o0; i < o1; ++i) atomicAdd(&cnt[(pk[i] >> 16) & 255], 1);
    }
    __syncthreads();
    int node = p * 256 + t;
    int c = cnt[t];
    if (node < N) deg[node] = c;
    red[t] = (c + 3) & ~3;
    __syncthreads();
    for (int off = 128; off > 0; off >>= 1) {
        if (t < off) red[t] += red[t + off];
        __syncthreads();
    }
    if (t == 0) partTot[p] = red[0];
}

// ---- scan over partition totals (nPart <= 256) ----
__global__ void part_scan_kernel(const int* __restrict__ partTot, int* __restrict__ partBase,
                                 int nPart) {
    __shared__ int sh[256];
    int t = threadIdx.x;
    int v = (t < nPart) ? partTot[t] : 0;
    sh[t] = v;
    __syncthreads();
    for (int off = 1; off < 256; off <<= 1) {
        int u = (t >= off) ? sh[t - off] : 0;
        __syncthreads();
        sh[t] += u;
        __syncthreads();
    }
    if (t < nPart) partBase[t] = sh[t] - v;
}

// ---- per-partition scatter: dense row_ptr + windowed src_idx writes ----
__global__ void binB_scatter_kernel(const unsigned int* __restrict__ packed,
                                    const int* __restrict__ offs, const int* __restrict__ deg,
                                    const int* __restrict__ partBase, int* __restrict__ row_ptr,
                                    unsigned short* __restrict__ src_idx, int nChunks, int N) {
    __shared__ int pref[256];
    __shared__ int cur[256];
    int t = threadIdx.x;
    int p = blockIdx.x;
    int node = p * 256 + t;
    int d = (node < N) ? deg[node] : 0;
    int a = (d + 3) & ~3;
    pref[t] = a;
    __syncthreads();
    for (int off = 1; off < 256; off <<= 1) {
        int u = (t >= off) ? pref[t - off] : 0;
        __syncthreads();
        pref[t] += u;
        __syncthreads();
    }
    int rp = partBase[p] + pref[t] - a;
    if (node < N) row_ptr[node] = rp;
    cur[t] = rp;
    __syncthreads();
    for (int c = t; c < nChunks; c += 256) {
        const int* oc = offs + c * 257;
        int o0 = oc[p], o1 = oc[p + 1];
        const unsigned int* pk = packed + (size_t)c * CHUNK;
        for (int i = o0; i < o1; ++i) {
            unsigned int pr = pk[i];
            int ln = (pr >> 16) & 255;
            int slot = atomicAdd(&cur[ln], 1);
            src_idx[slot] = (unsigned short)(pr & 0xffffu);
        }
    }
}

// x (fp32) -> x16 (fp16), one half8 per thread.
__global__ void cvt_x_kernel(const float* __restrict__ x, _Float16* __restrict__ x16, int total8) {
    int i = blockIdx.x * blockDim.x + threadIdx.x;
    if (i >= total8) return;
    float4 v0 = ((const float4*)x)[2 * i];
    float4 v1 = ((const float4*)x)[2 * i + 1];
    half8 o;
    o[0] = (_Float16)v0.x; o[1] = (_Float16)v0.y; o[2] = (_Float16)v0.z; o[3] = (_Float16)v0.w;
    o[4] = (_Float16)v1.x; o[5] = (_Float16)v1.y; o[6] = (_Float16)v1.z; o[7] = (_Float16)v1.w;
    ((half8*)x16)[i] = o;
}

// Mean aggregation over fp16 rows (128B = 8 lanes x half8). TWO nodes per
// wave: each 32-lane half = 4 groups x 8 lanes, 4 slots/group (ushort4).
__global__ void agg_mean8_kernel(const _Float16* __restrict__ h, const int* __restrict__ row_ptr,
                                 const int* __restrict__ degp,
                                 const unsigned short* __restrict__ src_idx,
                                 _Float16* __restrict__ h_out, int N) {
    int wid = (blockIdx.x * blockDim.x + threadIdx.x) >> 6;
    int lane = threadIdx.x & 63;
    int half = lane >> 5;
    int node = wid * 2 + half;
    if (node >= N) return;
    int lane32 = lane & 31;
    int beg = row_ptr[node];
    int dgr = degp[node];
    int end = beg + dgr;
    int j = lane32 >> 3, f = lane32 & 7;
    const uint4* rowp = (const uint4*)h;
    float acc[8];
    #pragma unroll
    for (int q = 0; q < 8; ++q) acc[q] = 0.f;
    for (int base = beg + 4 * j; base < end; base += 16) {
        ushort4 i4 = *(const ushort4*)(src_idx + base);   // base 4-aligned
        unsigned short ss[4] = {i4.x, i4.y, i4.z, i4.w};
        #pragma unroll
        for (int k = 0; k < 4; ++k) {
            int e = base + k;
            int s = ss[k];
            uint4 raw = rowp[(size_t)s * 8 + f];
            if (e >= end) { raw.x = 0u; raw.y = 0u; raw.z = 0u; raw.w = 0u; }
            half8 v = *(half8*)&raw;
            #pragma unroll
            for (int q = 0; q < 8; ++q) acc[q] += (float)v[q];
        }
    }
    #pragma unroll
    for (int q = 0; q < 8; ++q) {
        acc[q] += __shfl_down(acc[q], 16, 64);   // stays within the 32-lane half
        acc[q] += __shfl_down(acc[q], 8, 64);
    }
    if (lane32 < 8) {
        float inv = dgr > 0 ? 1.f / (float)dgr : 0.f;
        half8 o;
        #pragma unroll
        for (int q = 0; q < 8; ++q) o[q] = (_Float16)(acc[q] * inv);
        *((half8*)h_out + (size_t)node * 8 + lane32) = o;
    }
}

// Conv1 transform: xs = (x+h1+h2+h3)/4. z1 = xs@W_lin1 (fp16), a1/a2 dots.
__global__ void xform1_kernel(const float* __restrict__ x, const _Float16* __restrict__ hA,
                              const _Float16* __restrict__ hB, const _Float16* __restrict__ hC,
                              const float* __restrict__ W_lin1, const float* __restrict__ W_att1,
                              _Float16* __restrict__ z1, float* __restrict__ a1,
                              float* __restrict__ a2, int N) {
    __shared__ float row[4][64];
    int wib = threadIdx.x >> 6;
    int lane = threadIdx.x & 63;
    int n = blockIdx.x * 4 + wib;
    int nc = n < N ? n : N - 1;
    size_t idx = (size_t)nc * 64 + lane;
    float xv = (x[idx] + (float)hA[idx] + (float)hB[idx] + (float)hC[idx]) * 0.25f;
    row[wib][lane] = xv;
    __syncthreads();
    float p1 = xv * W_att1[lane];
    float p2 = xv * W_att1[64 + lane];
    for (int off = 32; off > 0; off >>= 1) {
        p1 += __shfl_down(p1, off, 64);
        p2 += __shfl_down(p2, off, 64);
    }
    float acc = 0.f;
    #pragma unroll
    for (int k = 0; k < 64; ++k) acc += row[wib][k] * W_lin1[k * 64 + lane];
    if (n < N) {
        z1[(size_t)n * 64 + lane] = (_Float16)acc;
        if (lane == 0) { a1[n] = p1; a2[n] = p2; }
    }
}

__global__ void xform2_kernel(const float* __restrict__ h1, const float* __restrict__ W_lin2,
                              const float* __restrict__ W_att2,
                              float* __restrict__ z2, float* __restrict__ a1, float* __restrict__ a2,
                              int N) {
    __shared__ float row[4][64];
    int wib = threadIdx.x >> 6;
    int lane = threadIdx.x & 63;
    int n = blockIdx.x * 4 + wib;
    int nc = n < N ? n : N - 1;
    float hv = h1[(size_t)nc * 64 + lane];
    row[wib][lane] = hv;
    __syncthreads();
    float p1 = hv * W_att2[lane];
    float p2 = hv * W_att2[64 + lane];
    for (int off = 32; off > 0; off >>= 1) {
        p1 += __shfl_down(p1, off, 64);
        p2 += __shfl_down(p2, off, 64);
    }
    float acc = 0.f;
    if (lane < 32) {
        #pragma unroll
        for (int k = 0; k < 64; ++k) acc += row[wib][k] * W_lin2[k * 32 + lane];
    }
    if (n < N) {
        if (lane < 32) z2[(size_t)n * 32 + lane] = acc;
        if (lane == 0) { a1[n] = p1; a2[n] = p2; }
    }
}

// Conv1 aggregation: fp16 z1 rows, two nodes per wave, per-edge leaky score,
// relu -> fp32 out.
__global__ void agg_conv64_kernel(const _Float16* __restrict__ z, const float* __restrict__ a1v,
                                  const float* __restrict__ a2v, const float* __restrict__ b_att,
                                  const int* __restrict__ row_ptr, const int* __restrict__ degp,
                                  const unsigned short* __restrict__ src_idx,
                                  float* __restrict__ outp, int N) {
    int wid = (blockIdx.x * blockDim.x + threadIdx.x) >> 6;
    int lane = threadIdx.x & 63;
    int half = lane >> 5;
    int node = wid * 2 + half;
    if (node >= N) return;
    int lane32 = lane & 31;
    float ad = a2v[node] + b_att[0];
    int beg = row_ptr[node];
    int end = beg + degp[node];
    int j = lane32 >> 3, f = lane32 & 7;
    const uint4* rowp = (const uint4*)z;
    float acc[8];
    #pragma unroll
    for (int q = 0; q < 8; ++q) acc[q] = 0.f;
    for (int base = beg + 4 * j; base < end; base += 16) {
        ushort4 i4 = *(const ushort4*)(src_idx + base);
        unsigned short ss[4] = {i4.x, i4.y, i4.z, i4.w};
        #pragma unroll
        for (int k = 0; k < 4; ++k) {
            int e = base + k;
            int s = ss[k];
            float sc = a1v[s] + ad;
            sc = sc > 0.f ? sc : 0.01f * sc;
            uint4 raw = rowp[(size_t)s * 8 + f];
            if (e >= end) { raw.x = 0u; raw.y = 0u; raw.z = 0u; raw.w = 0u; }
            half8 v = *(half8*)&raw;
            #pragma unroll
            for (int q = 0; q < 8; ++q) acc[q] += sc * (float)v[q];
        }
    }
    #pragma unroll
    for (int q = 0; q < 8; ++q) {
        acc[q] += __shfl_down(acc[q], 16, 64);
        acc[q] += __shfl_down(acc[q], 8, 64);
    }
    if (lane32 < 8) {
        float4 o0, o1;
        o0.x = fmaxf(acc[0], 0.f); o0.y = fmaxf(acc[1], 0.f);
        o0.z = fmaxf(acc[2], 0.f); o0.w = fmaxf(acc[3], 0.f);
        o1.x = fmaxf(acc[4], 0.f); o1.y = fmaxf(acc[5], 0.f);
        o1.z = fmaxf(acc[6], 0.f); o1.w = fmaxf(acc[7], 0.f);
        float4* op = (float4*)(outp + (size_t)node * 64 + lane32 * 8);
        op[0] = o0; op[1] = o1;
    }
}

// Conv2 aggregation: fp32 z2 rows (128B = 8 lanes x float4), two nodes/wave.
__global__ void agg_conv32_kernel(const float* __restrict__ z, const float* __restrict__ a1v,
                                  const float* __restrict__ a2v, const float* __restrict__ b_att,
                                  const int* __restrict__ row_ptr, const int* __restrict__ degp,
                                  const unsigned short* __restrict__ src_idx,
                                  float* __restrict__ outp, int N) {
    int wid = (blockIdx.x * blockDim.x + threadIdx.x) >> 6;
    int lane = threadIdx.x & 63;
    int half = lane >> 5;
    int node = wid * 2 + half;
    if (node >= N) return;
    int lane32 = lane & 31;
    float ad = a2v[node] + b_att[0];
    int beg = row_ptr[node];
    int end = beg + degp[node];
    int j = lane32 >> 3, f = lane32 & 7;
    const float4* rowp = (const float4*)z;
    float ax = 0.f, ay = 0.f, az = 0.f, aw = 0.f;
    for (int base = beg + 4 * j; base < end; base += 16) {
        ushort4 i4 = *(const ushort4*)(src_idx + base);
        unsigned short ss[4] = {i4.x, i4.y, i4.z, i4.w};
        #pragma unroll
        for (int k = 0; k < 4; ++k) {
            int e = base + k;
            int s = ss[k];
            float sc = a1v[s] + ad;
            sc = sc > 0.f ? sc : 0.01f * sc;
            if (e >= end) sc = 0.f;
            float4 v = rowp[(size_t)s * 8 + f];
            ax += sc * v.x; ay += sc * v.y; az += sc * v.z; aw += sc * v.w;
        }
    }
    ax += __shfl_down(ax, 16, 64); ay += __shfl_down(ay, 16, 64);
    az += __shfl_down(az, 16, 64); aw += __shfl_down(aw, 16, 64);
    ax += __shfl_down(ax, 8, 64);  ay += __shfl_down(ay, 8, 64);
    az += __shfl_down(az, 8, 64);  aw += __shfl_down(aw, 8, 64);
    if (lane32 < 8) {
        float4 o; o.x = ax; o.y = ay; o.z = az; o.w = aw;
        *((float4*)(outp + (size_t)node * 32) + lane32) = o;
    }
}

extern "C" void kernel_launch(void* const* d_in, const int* in_sizes, int n_in,
                              void* d_out, int out_size, void* d_ws, size_t ws_size,
                              hipStream_t stream) {
    const float* x      = (const float*)d_in[0];
    const int*   ei     = (const int*)d_in[1];
    const float* W_att1 = (const float*)d_in[2];
    const float* b_att1 = (const float*)d_in[3];
    const float* W_lin1 = (const float*)d_in[4];
    const float* W_att2 = (const float*)d_in[5];
    const float* b_att2 = (const float*)d_in[6];
    const float* W_lin2 = (const float*)d_in[7];
    float* out = (float*)d_out;

    int N = in_sizes[0] / 64;   // 50000 (< 65536, required for u16 indices)
    int E = in_sizes[1] / 2;
    const int* src = ei;
    const int* dst = ei + E;
    int nChunks = (E + CHUNK - 1) / CHUNK;   // 391
    int nPart   = (N + 255) >> 8;            // 196 (must be <= 256)

    char* ws = (char*)d_ws;
    size_t off = 0;
    auto alloc = [&](size_t bytes) -> void* {
        void* p = ws + off;
        off += (bytes + 255) & ~(size_t)255;
        return p;
    };
    int*            deg      = (int*)alloc((size_t)N * 4);
    int*            row_ptr  = (int*)alloc((size_t)N * 4);
    unsigned short* src_idx  = (unsigned short*)alloc(((size_t)E + 4 * N) * 2);
    unsigned int*   packed   = (unsigned int*)alloc((size_t)nChunks * CHUNK * 4);
    int*            offs     = (int*)alloc((size_t)nChunks * 257 * 4);
    int*            partTot  = (int*)alloc((size_t)256 * 4);
    int*            partBase = (int*)alloc((size_t)256 * 4);
    _Float16* x16 = (_Float16*)alloc((size_t)N * 64 * 2);
    _Float16* hA  = (_Float16*)alloc((size_t)N * 64 * 2);
    _Float16* hB  = (_Float16*)alloc((size_t)N * 64 * 2);
    _Float16* hC  = (_Float16*)alloc((size_t)N * 64 * 2);
    _Float16* z1  = (_Float16*)alloc((size_t)N * 64 * 2);
    float* h1c = (float*)alloc((size_t)N * 64 * 4);
    float* z2  = (float*)alloc((size_t)N * 32 * 4);
    float* a1  = (float*)alloc((size_t)N * 4);
    float* a2  = (float*)alloc((size_t)N * 4);
    float* a1b = (float*)alloc((size_t)N * 4);
    float* a2b = (float*)alloc((size_t)N * 4);

    const int tb = 256;

    binA_kernel<<<nChunks, 256, 0, stream>>>(src, dst, packed, offs, E);
    binB_count_kernel<<<nPart, 256, 0, stream>>>(packed, offs, deg, partTot, nChunks, N);
    part_scan_kernel<<<1, 256, 0, stream>>>(partTot, partBase, nPart);
    binB_scatter_kernel<<<nPart, 256, 0, stream>>>(packed, offs, deg, partBase, row_ptr,
                                                   src_idx, nChunks, N);

    int total8 = N * 8;
    cvt_x_kernel<<<(total8 + tb - 1) / tb, tb, 0, stream>>>(x, x16, total8);

    int gBlocks = (N + 7) / 8;      // two nodes per wave, 4 waves/block
    int xBlocks = (N + 3) / 4;      // one node per wave (transforms)
    agg_mean8_kernel<<<gBlocks, tb, 0, stream>>>(x16, row_ptr, deg, src_idx, hA, N);
    agg_mean8_kernel<<<gBlocks, tb, 0, stream>>>(hA,  row_ptr, deg, src_idx, hB, N);
    agg_mean8_kernel<<<gBlocks, tb, 0, stream>>>(hB,  row_ptr, deg, src_idx, hC, N);

    xform1_kernel<<<xBlocks, tb, 0, stream>>>(x, hA, hB, hC, W_lin1, W_att1,
                                              z1, a1, a2, N);
    agg_conv64_kernel<<<gBlocks, tb, 0, stream>>>(z1, a1, a2, b_att1, row_ptr, deg, src_idx,
                                                  h1c, N);
    xform2_kernel<<<xBlocks, tb, 0, stream>>>(h1c, W_lin2, W_att2, z2, a1b, a2b, N);
    agg_conv32_kernel<<<gBlocks, tb, 0, stream>>>(z2, a1b, a2b, b_att2, row_ptr, deg, src_idx,
                                                  out, N);
}

// Round 11
// 242.080 us; speedup vs baseline: 1.6727x; 1.0568x over previous
//
#include <hip/hip_runtime.h>

// DeformableGCN: 3x mean-smoothing + 2x attention-weighted GCN conv.
// R7: 8-lane-group half8/float4 gathers, branchless predication.
// R8/R9: partition-parallel LDS bin-sort CSR; ushort4 index loads.
// R10: two nodes per wave in gathers (32-lane half per node).
// R11: wave-local fusion — xform1 into mean pass 3, xform2 into conv64
// (weights staged in LDS with ONE sync at kernel start; no post-gather
// __syncthreads, so no block max-degree coupling). part_scan folded into
// binB_scatter; cvt_x folded into binA. 12 -> 8 dispatches; hC and h1c
// round-trips eliminated.

typedef __attribute__((ext_vector_type(8))) _Float16 half8;

#define CHUNK 2048

// ---- pass A: bin edges into partition-sorted chunks + x->fp16 convert ----
__global__ void binA_kernel(const int* __restrict__ src, const int* __restrict__ dst,
                            unsigned int* __restrict__ packed, int* __restrict__ offs,
                            const float* __restrict__ x, _Float16* __restrict__ x16,
                            int total8, int E) {
    __shared__ int cnt[256];
    __shared__ int pref[256];
    __shared__ int cur[256];
    __shared__ unsigned int stage[CHUNK];
    int t = threadIdx.x;
    int base = blockIdx.x * CHUNK;
    int len = E - base; if (len > CHUNK) len = CHUNK;
    cnt[t] = 0;
    __syncthreads();
    for (int i = t; i < len; i += 256) atomicAdd(&cnt[dst[base + i] >> 8], 1);
    __syncthreads();
    int v = cnt[t];
    pref[t] = v;
    __syncthreads();
    for (int off = 1; off < 256; off <<= 1) {
        int u = (t >= off) ? pref[t - off] : 0;
        __syncthreads();
        pref[t] += u;
        __syncthreads();
    }
    int excl = pref[t] - v;
    cur[t] = excl;
    offs[blockIdx.x * 257 + t] = excl;
    if (t == 255) offs[blockIdx.x * 257 + 256] = pref[255];
    __syncthreads();
    for (int i = t; i < len; i += 256) {
        int s = src[base + i], d = dst[base + i];
        int pos = atomicAdd(&cur[d >> 8], 1);
        stage[pos] = (unsigned int)s | ((unsigned int)d << 16);
    }
    __syncthreads();
    for (int i = t; i < len; i += 256) packed[base + i] = stage[i];
    // grid-stride x -> fp16 conversion tail
    for (int i = blockIdx.x * 256 + t; i < total8; i += gridDim.x * 256) {
        float4 v0 = ((const float4*)x)[2 * i];
        float4 v1 = ((const float4*)x)[2 * i + 1];
        half8 o;
        o[0] = (_Float16)v0.x; o[1] = (_Float16)v0.y; o[2] = (_Float16)v0.z; o[3] = (_Float16)v0.w;
        o[4] = (_Float16)v1.x; o[5] = (_Float16)v1.y; o[6] = (_Float16)v1.z; o[7] = (_Float16)v1.w;
        ((half8*)x16)[i] = o;
    }
}

// ---- per-partition degree count: dense deg write + aligned total ----
__global__ void binB_count_kernel(const unsigned int* __restrict__ packed,
                                  const int* __restrict__ offs,
                                  int* __restrict__ deg, int* __restrict__ partTot,
                                  int nChunks, int N) {
    __shared__ int cnt[256];
    __shared__ int red[256];
    int t = threadIdx.x;
    int p = blockIdx.x;
    cnt[t] = 0;
    __syncthreads();
    for (int c = t; c < nChunks; c += 256) {
        const int* oc = offs + c * 257;
        int o0 = oc[p], o1 = oc[p + 1];
        const unsigned int* pk = packed + (size_t)c * CHUNK;
        for (int i = o0; i < o1; ++i) atomicAdd(&cnt[(pk[i] >> 16) & 255], 1);
    }
    __syncthreads();
    int node = p * 256 + t;
    int c = cnt[t];
    if (node < N) deg[node] = c;
    red[t] = (c + 3) & ~3;
    __syncthreads();
    for (int off = 128; off > 0; off >>= 1) {
        if (t < off) red[t] += red[t + off];
        __syncthreads();
    }
    if (t == 0) partTot[p] = red[0];
}

// ---- per-partition scatter (partition-base scan folded in) ----
__global__ void binB_scatter_kernel(const unsigned int* __restrict__ packed,
                                    const int* __restrict__ offs, const int* __restrict__ deg,
                                    const int* __restrict__ partTot, int* __restrict__ row_ptr,
                                    unsigned short* __restrict__ src_idx, int nChunks,
                                    int nPart, int N) {
    __shared__ int ps[256];
    __shared__ int pref[256];
    __shared__ int cur[256];
    int t = threadIdx.x;
    int p = blockIdx.x;
    // redundant per-block scan of partition totals -> this partition's base
    ps[t] = (t < nPart) ? partTot[t] : 0;
    __syncthreads();
    for (int off = 1; off < 256; off <<= 1) {
        int u = (t >= off) ? ps[t - off] : 0;
        __syncthreads();
        ps[t] += u;
        __syncthreads();
    }
    int partBase = (p > 0) ? ps[p - 1] : 0;
    int node = p * 256 + t;
    int d = (node < N) ? deg[node] : 0;
    int a = (d + 3) & ~3;
    pref[t] = a;
    __syncthreads();
    for (int off = 1; off < 256; off <<= 1) {
        int u = (t >= off) ? pref[t - off] : 0;
        __syncthreads();
        pref[t] += u;
        __syncthreads();
    }
    int rp = partBase + pref[t] - a;
    if (node < N) row_ptr[node] = rp;
    cur[t] = rp;
    __syncthreads();
    for (int c = t; c < nChunks; c += 256) {
        const int* oc = offs + c * 257;
        int o0 = oc[p], o1 = oc[p + 1];
        const unsigned int* pk = packed + (size_t)c * CHUNK;
        for (int i = o0; i < o1; ++i) {
            unsigned int pr = pk[i];
            int ln = (pr >> 16) & 255;
            int slot = atomicAdd(&cur[ln], 1);
            src_idx[slot] = (unsigned short)(pr & 0xffffu);
        }
    }
}

// Mean aggregation over fp16 rows. Two nodes per wave; each 32-lane half:
// 4 groups x 8 lanes, 4 predicated slots/group (ushort4 index load).
__global__ void agg_mean8_kernel(const _Float16* __restrict__ h, const int* __restrict__ row_ptr,
                                 const int* __restrict__ degp,
                                 const unsigned short* __restrict__ src_idx,
                                 _Float16* __restrict__ h_out, int N) {
    int wid = (blockIdx.x * blockDim.x + threadIdx.x) >> 6;
    int lane = threadIdx.x & 63;
    int node = wid * 2 + (lane >> 5);
    if (node >= N) return;
    int lane32 = lane & 31;
    int beg = row_ptr[node];
    int dgr = degp[node];
    int end = beg + dgr;
    int j = lane32 >> 3, f = lane32 & 7;
    const uint4* rowp = (const uint4*)h;
    float acc[8];
    #pragma unroll
    for (int q = 0; q < 8; ++q) acc[q] = 0.f;
    for (int base = beg + 4 * j; base < end; base += 16) {
        ushort4 i4 = *(const ushort4*)(src_idx + base);
        unsigned short ss[4] = {i4.x, i4.y, i4.z, i4.w};
        #pragma unroll
        for (int k = 0; k < 4; ++k) {
            int e = base + k;
            int s = ss[k];
            uint4 raw = rowp[(size_t)s * 8 + f];
            if (e >= end) { raw.x = 0u; raw.y = 0u; raw.z = 0u; raw.w = 0u; }
            half8 v = *(half8*)&raw;
            #pragma unroll
            for (int q = 0; q < 8; ++q) acc[q] += (float)v[q];
        }
    }
    #pragma unroll
    for (int q = 0; q < 8; ++q) {
        acc[q] += __shfl_down(acc[q], 16, 64);
        acc[q] += __shfl_down(acc[q], 8, 64);
    }
    if (lane32 < 8) {
        float inv = dgr > 0 ? 1.f / (float)dgr : 0.f;
        half8 o;
        #pragma unroll
        for (int q = 0; q < 8; ++q) o[q] = (_Float16)(acc[q] * inv);
        *((half8*)h_out + (size_t)node * 8 + lane32) = o;
    }
}

// Fused: smoothing pass 3 + conv1 transform. Gather h3 (registers), build
// xs = (x+h1+h2+h3)/4 on lanes 0-7 of each half, attention dots via in-half
// shuffles, z1 = xs@W_lin1 via 64-step broadcast GEMV (W_lin1 in LDS).
// Only sync is the initial weight-staging barrier (before variable work).
__global__ void mean3_xf1_kernel(const _Float16* __restrict__ h /*h2*/,
                                 const _Float16* __restrict__ x16,
                                 const _Float16* __restrict__ hA /*h1*/,
                                 const int* __restrict__ row_ptr, const int* __restrict__ degp,
                                 const unsigned short* __restrict__ src_idx,
                                 const float* __restrict__ W_lin1,
                                 const float* __restrict__ W_att1,
                                 _Float16* __restrict__ z1, float* __restrict__ a1,
                                 float* __restrict__ a2, int N) {
    __shared__ float Wl[64 * 64];
    __shared__ float Wa[128];
    for (int i = threadIdx.x; i < 64 * 64; i += 256) Wl[i] = W_lin1[i];
    if (threadIdx.x < 128) Wa[threadIdx.x] = W_att1[threadIdx.x];
    __syncthreads();
    int wid = (blockIdx.x * blockDim.x + threadIdx.x) >> 6;
    int lane = threadIdx.x & 63;
    int node = wid * 2 + (lane >> 5);
    if (node >= N) return;
    int lane32 = lane & 31;
    int beg = row_ptr[node];
    int dgr = degp[node];
    int end = beg + dgr;
    int j = lane32 >> 3, f = lane32 & 7;
    const uint4* rowp = (const uint4*)h;
    float acc[8];
    #pragma unroll
    for (int q = 0; q < 8; ++q) acc[q] = 0.f;
    for (int base = beg + 4 * j; base < end; base += 16) {
        ushort4 i4 = *(const ushort4*)(src_idx + base);
        unsigned short ss[4] = {i4.x, i4.y, i4.z, i4.w};
        #pragma unroll
        for (int k = 0; k < 4; ++k) {
            int e = base + k;
            int s = ss[k];
            uint4 raw = rowp[(size_t)s * 8 + f];
            if (e >= end) { raw.x = 0u; raw.y = 0u; raw.z = 0u; raw.w = 0u; }
            half8 v = *(half8*)&raw;
            #pragma unroll
            for (int q = 0; q < 8; ++q) acc[q] += (float)v[q];
        }
    }
    #pragma unroll
    for (int q = 0; q < 8; ++q) {
        acc[q] += __shfl_down(acc[q], 16, 64);
        acc[q] += __shfl_down(acc[q], 8, 64);
    }
    // xs on lanes 0-7 of each half (feature block f*8..f*8+7)
    float xs[8];
    #pragma unroll
    for (int q = 0; q < 8; ++q) xs[q] = 0.f;
    float p1 = 0.f, p2 = 0.f;
    if (lane32 < 8) {
        float inv = dgr > 0 ? 1.f / (float)dgr : 0.f;
        half8 xv = *((const half8*)x16 + (size_t)node * 8 + f);
        half8 h1v = *((const half8*)hA + (size_t)node * 8 + f);
        half8 h2v = *((const half8*)h + (size_t)node * 8 + f);
        #pragma unroll
        for (int q = 0; q < 8; ++q) {
            xs[q] = ((float)xv[q] + (float)h1v[q] + (float)h2v[q] + acc[q] * inv) * 0.25f;
            p1 += xs[q] * Wa[f * 8 + q];
            p2 += xs[q] * Wa[64 + f * 8 + q];
        }
    }
    p1 += __shfl_down(p1, 4, 64); p2 += __shfl_down(p2, 4, 64);
    p1 += __shfl_down(p1, 2, 64); p2 += __shfl_down(p2, 2, 64);
    p1 += __shfl_down(p1, 1, 64); p2 += __shfl_down(p2, 1, 64);
    if (lane32 == 0) { a1[node] = p1; a2[node] = p2; }
    // z1 = xs @ W_lin1: broadcast xs_k from owning lane, 2 outputs per lane
    float z0 = 0.f, zb = 0.f;
    int srcBase = lane & 32;
    #pragma unroll
    for (int k = 0; k < 64; ++k) {
        float xk = __shfl(xs[k & 7], srcBase + (k >> 3), 64);
        z0 += xk * Wl[k * 64 + lane32];
        zb += xk * Wl[k * 64 + 32 + lane32];
    }
    z1[(size_t)node * 64 + lane32] = (_Float16)z0;
    z1[(size_t)node * 64 + 32 + lane32] = (_Float16)zb;
}

// Fused: conv1 aggregation + conv2 transform. Gather z1 with leaky scores,
// relu -> h1 in registers, attention dots, z2 = h1@W_lin2 (LDS GEMV).
__global__ void conv64_xf2_kernel(const _Float16* __restrict__ z, const float* __restrict__ a1v,
                                  const float* __restrict__ a2v, const float* __restrict__ b_att,
                                  const int* __restrict__ row_ptr, const int* __restrict__ degp,
                                  const unsigned short* __restrict__ src_idx,
                                  const float* __restrict__ W_lin2,
                                  const float* __restrict__ W_att2,
                                  float* __restrict__ z2, float* __restrict__ a1o,
                                  float* __restrict__ a2o, int N) {
    __shared__ float Wl[64 * 32];
    __shared__ float Wa[128];
    for (int i = threadIdx.x; i < 64 * 32; i += 256) Wl[i] = W_lin2[i];
    if (threadIdx.x < 128) Wa[threadIdx.x] = W_att2[threadIdx.x];
    __syncthreads();
    int wid = (blockIdx.x * blockDim.x + threadIdx.x) >> 6;
    int lane = threadIdx.x & 63;
    int node = wid * 2 + (lane >> 5);
    if (node >= N) return;
    int lane32 = lane & 31;
    float ad = a2v[node] + b_att[0];
    int beg = row_ptr[node];
    int dgr = degp[node];
    int end = beg + dgr;
    int j = lane32 >> 3, f = lane32 & 7;
    const uint4* rowp = (const uint4*)z;
    float acc[8];
    #pragma unroll
    for (int q = 0; q < 8; ++q) acc[q] = 0.f;
    for (int base = beg + 4 * j; base < end; base += 16) {
        ushort4 i4 = *(const ushort4*)(src_idx + base);
        unsigned short ss[4] = {i4.x, i4.y, i4.z, i4.w};
        #pragma unroll
        for (int k = 0; k < 4; ++k) {
            int e = base + k;
            int s = ss[k];
            float sc = a1v[s] + ad;
            sc = sc > 0.f ? sc : 0.01f * sc;
            uint4 raw = rowp[(size_t)s * 8 + f];
            if (e >= end) { raw.x = 0u; raw.y = 0u; raw.z = 0u; raw.w = 0u; }
            half8 v = *(half8*)&raw;
            #pragma unroll
            for (int q = 0; q < 8; ++q) acc[q] += sc * (float)v[q];
        }
    }
    #pragma unroll
    for (int q = 0; q < 8; ++q) {
        acc[q] += __shfl_down(acc[q], 16, 64);
        acc[q] += __shfl_down(acc[q], 8, 64);
    }
    // h1 = relu(feats) on lanes 0-7; attention dots
    float hreg[8];
    #pragma unroll
    for (int q = 0; q < 8; ++q) hreg[q] = 0.f;
    float p1 = 0.f, p2 = 0.f;
    if (lane32 < 8) {
        #pragma unroll
        for (int q = 0; q < 8; ++q) {
            hreg[q] = fmaxf(acc[q], 0.f);
            p1 += hreg[q] * Wa[f * 8 + q];
            p2 += hreg[q] * Wa[64 + f * 8 + q];
        }
    }
    p1 += __shfl_down(p1, 4, 64); p2 += __shfl_down(p2, 4, 64);
    p1 += __shfl_down(p1, 2, 64); p2 += __shfl_down(p2, 2, 64);
    p1 += __shfl_down(p1, 1, 64); p2 += __shfl_down(p2, 1, 64);
    if (lane32 == 0) { a1o[node] = p1; a2o[node] = p2; }
    // z2 = h1 @ W_lin2 (64x32): 1 output per lane
    float zacc = 0.f;
    int srcBase = lane & 32;
    #pragma unroll
    for (int k = 0; k < 64; ++k) {
        float hk = __shfl(hreg[k & 7], srcBase + (k >> 3), 64);
        zacc += hk * Wl[k * 32 + lane32];
    }
    z2[(size_t)node * 32 + lane32] = zacc;
}

// Conv2 aggregation: fp32 z2 rows (128B = 8 lanes x float4), two nodes/wave.
__global__ void agg_conv32_kernel(const float* __restrict__ z, const float* __restrict__ a1v,
                                  const float* __restrict__ a2v, const float* __restrict__ b_att,
                                  const int* __restrict__ row_ptr, const int* __restrict__ degp,
                                  const unsigned short* __restrict__ src_idx,
                                  float* __restrict__ outp, int N) {
    int wid = (blockIdx.x * blockDim.x + threadIdx.x) >> 6;
    int lane = threadIdx.x & 63;
    int node = wid * 2 + (lane >> 5);
    if (node >= N) return;
    int lane32 = lane & 31;
    float ad = a2v[node] + b_att[0];
    int beg = row_ptr[node];
    int end = beg + degp[node];
    int j = lane32 >> 3, f = lane32 & 7;
    const float4* rowp = (const float4*)z;
    float ax = 0.f, ay = 0.f, az = 0.f, aw = 0.f;
    for (int base = beg + 4 * j; base < end; base += 16) {
        ushort4 i4 = *(const ushort4*)(src_idx + base);
        unsigned short ss[4] = {i4.x, i4.y, i4.z, i4.w};
        #pragma unroll
        for (int k = 0; k < 4; ++k) {
            int e = base + k;
            int s = ss[k];
            float sc = a1v[s] + ad;
            sc = sc > 0.f ? sc : 0.01f * sc;
            if (e >= end) sc = 0.f;
            float4 v = rowp[(size_t)s * 8 + f];
            ax += sc * v.x; ay += sc * v.y; az += sc * v.z; aw += sc * v.w;
        }
    }
    ax += __shfl_down(ax, 16, 64); ay += __shfl_down(ay, 16, 64);
    az += __shfl_down(az, 16, 64); aw += __shfl_down(aw, 16, 64);
    ax += __shfl_down(ax, 8, 64);  ay += __shfl_down(ay, 8, 64);
    az += __shfl_down(az, 8, 64);  aw += __shfl_down(aw, 8, 64);
    if (lane32 < 8) {
        float4 o; o.x = ax; o.y = ay; o.z = az; o.w = aw;
        *((float4*)(outp + (size_t)node * 32) + lane32) = o;
    }
}

extern "C" void kernel_launch(void* const* d_in, const int* in_sizes, int n_in,
                              void* d_out, int out_size, void* d_ws, size_t ws_size,
                              hipStream_t stream) {
    const float* x      = (const float*)d_in[0];
    const int*   ei     = (const int*)d_in[1];
    const float* W_att1 = (const float*)d_in[2];
    const float* b_att1 = (const float*)d_in[3];
    const float* W_lin1 = (const float*)d_in[4];
    const float* W_att2 = (const float*)d_in[5];
    const float* b_att2 = (const float*)d_in[6];
    const float* W_lin2 = (const float*)d_in[7];
    float* out = (float*)d_out;

    int N = in_sizes[0] / 64;   // 50000 (< 65536, required for u16 indices)
    int E = in_sizes[1] / 2;
    const int* src = ei;
    const int* dst = ei + E;
    int nChunks = (E + CHUNK - 1) / CHUNK;   // 391
    int nPart   = (N + 255) >> 8;            // 196 (must be <= 256)

    char* ws = (char*)d_ws;
    size_t off = 0;
    auto alloc = [&](size_t bytes) -> void* {
        void* p = ws + off;
        off += (bytes + 255) & ~(size_t)255;
        return p;
    };
    int*            deg     = (int*)alloc((size_t)N * 4);
    int*            row_ptr = (int*)alloc((size_t)N * 4);
    unsigned short* src_idx = (unsigned short*)alloc(((size_t)E + 4 * N) * 2);
    unsigned int*   packed  = (unsigned int*)alloc((size_t)nChunks * CHUNK * 4);
    int*            offs    = (int*)alloc((size_t)nChunks * 257 * 4);
    int*            partTot = (int*)alloc((size_t)256 * 4);
    _Float16* x16 = (_Float16*)alloc((size_t)N * 64 * 2);
    _Float16* hA  = (_Float16*)alloc((size_t)N * 64 * 2);
    _Float16* hB  = (_Float16*)alloc((size_t)N * 64 * 2);
    _Float16* z1  = (_Float16*)alloc((size_t)N * 64 * 2);
    float* z2  = (float*)alloc((size_t)N * 32 * 4);
    float* a1  = (float*)alloc((size_t)N * 4);
    float* a2  = (float*)alloc((size_t)N * 4);
    float* a1b = (float*)alloc((size_t)N * 4);
    float* a2b = (float*)alloc((size_t)N * 4);

    const int tb = 256;
    int total8 = N * 8;

    binA_kernel<<<nChunks, 256, 0, stream>>>(src, dst, packed, offs, x, x16, total8, E);
    binB_count_kernel<<<nPart, 256, 0, stream>>>(packed, offs, deg, partTot, nChunks, N);
    binB_scatter_kernel<<<nPart, 256, 0, stream>>>(packed, offs, deg, partTot, row_ptr,
                                                   src_idx, nChunks, nPart, N);

    int gBlocks = (N + 7) / 8;   // two nodes per wave, 4 waves/block
    agg_mean8_kernel<<<gBlocks, tb, 0, stream>>>(x16, row_ptr, deg, src_idx, hA, N);
    agg_mean8_kernel<<<gBlocks, tb, 0, stream>>>(hA,  row_ptr, deg, src_idx, hB, N);
    mean3_xf1_kernel<<<gBlocks, tb, 0, stream>>>(hB, x16, hA, row_ptr, deg, src_idx,
                                                 W_lin1, W_att1, z1, a1, a2, N);
    conv64_xf2_kernel<<<gBlocks, tb, 0, stream>>>(z1, a1, a2, b_att1, row_ptr, deg, src_idx,
                                                  W_lin2, W_att2, z2, a1b, a2b, N);
    agg_conv32_kernel<<<gBlocks, tb, 0, stream>>>(z2, a1b, a2b, b_att2, row_ptr, deg, src_idx,
                                                  out, N);
}